// Round 10
// baseline (653.284 us; speedup 1.0000x reference)
//
#include <hip/hip_runtime.h>

// ---------------------------------------------------------------------------
// NucleusMoEImageTransformerBlock round 10.
// B=2 SI=1024 ST=512 D=2048 H=16 KV=4 HD=128 E=8 F=1024 TOPK=2
// Round-10: fix the MoE work->CU concentration trap. r8/r9 put bm in the
// LOW bits of the work index; with CU assignment idx-ordered in stride-32
// rounds, working bm-slots aliased onto 8 CUs/XCD (both rounds: identical
// 99us). New MoE kernel: 128x256 tile, bn in low bits (working blocks
// contiguous in idx -> first round covers all 32 CUs/XCD), one expert per
// XCD, counted-vmcnt dbuf, 256 threads / 4 waves of 128x64.
// ---------------------------------------------------------------------------

typedef __attribute__((ext_vector_type(8))) __bf16 bf16x8;
typedef __attribute__((ext_vector_type(8))) unsigned short u16x8;
typedef __attribute__((ext_vector_type(4))) float f32x4;

__device__ __forceinline__ unsigned short f2bf(float x) {
  unsigned u = __builtin_bit_cast(unsigned, x);
  u += 0x7fffu + ((u >> 16) & 1u);        // RNE
  return (unsigned short)(u >> 16);
}
__device__ __forceinline__ float bf2f(unsigned short b) {
  return __builtin_bit_cast(float, ((unsigned)b) << 16);
}

__device__ __forceinline__ void glds16(const unsigned short* g, unsigned short* l) {
  __builtin_amdgcn_global_load_lds(
      (const __attribute__((address_space(1))) void*)g,
      (__attribute__((address_space(3))) void*)l, 16, 0, 0);
}

// m204 bijective XCD chunk swizzle.
__device__ __forceinline__ int xcd_swz(int orig, int nwg) {
  int q = nwg >> 3, r = nwg & 7;
  int xcd = orig & 7, idx = orig >> 3;
  int base = (xcd < r) ? xcd * (q + 1) : r * (q + 1) + (xcd - r) * q;
  return base + idx;
}

// ---------------------------------------------------------------------------
// Weight convert+transpose: W f32 [K][N] -> WT bf16 [N][K].
// ---------------------------------------------------------------------------
__global__ __launch_bounds__(256) void convert_w(
    const float* __restrict__ W, unsigned short* __restrict__ WT,
    int K, int N)
{
  __shared__ unsigned short T[64][66];
  const float* Wz = W + (size_t)blockIdx.z * K * N;
  unsigned short* WTz = WT + (size_t)blockIdx.z * K * N;
  const int k0 = blockIdx.x * 64, n0 = blockIdx.y * 64;
  const int tid = threadIdx.x;
  #pragma unroll
  for (int i = tid; i < 64 * 16; i += 256) {
    int k = i >> 4, n4 = (i & 15) * 4;
    float4 v = *(const float4*)&Wz[(size_t)(k0 + k) * N + n0 + n4];
    T[n4 + 0][k] = f2bf(v.x);
    T[n4 + 1][k] = f2bf(v.y);
    T[n4 + 2][k] = f2bf(v.z);
    T[n4 + 3][k] = f2bf(v.w);
  }
  __syncthreads();
  #pragma unroll
  for (int i = tid; i < 64 * 8; i += 256) {
    int n = i >> 3, k8 = (i & 7) * 8;
    *(u16x8*)&WTz[(size_t)(n0 + n) * K + k0 + k8] = *(const u16x8*)&T[n][k8];
  }
}

// ---------------------------------------------------------------------------
// Dense GEMM: C[M,N] = A[M,K] @ BT[N,K]^T (+resid). bf16 in, f32 out.
// 128x128 tile, counted-vmcnt dbuf pipeline (unchanged from r8).
// ---------------------------------------------------------------------------
__global__ __launch_bounds__(256) void gemm_bb(
    const unsigned short* __restrict__ A, const unsigned short* __restrict__ BT,
    float* __restrict__ C, const float* __restrict__ resid,
    int M, int N, int K)
{
  __shared__ unsigned short As[2][128 * 64];
  __shared__ unsigned short Bs[2][128 * 64];
  const int mb = M >> 7;
  const int w = xcd_swz(blockIdx.x, gridDim.x);
  const int bm = (w % mb) * 128, bn = (w / mb) * 128;
  const int tid = threadIdx.x, lane = tid & 63, wid = tid >> 6;
  const int wm = (wid >> 1) * 64, wn = (wid & 1) * 64;
  const int l16 = lane & 15, g4 = lane >> 4;
  const int rseg = lane >> 3;
  const int csw  = ((lane & 7) ^ rseg) * 8;
  const unsigned short* aSrc[4];
  const unsigned short* bSrc[4];
  #pragma unroll
  for (int p = 0; p < 4; ++p) {
    int row = (p * 4 + wid) * 8 + rseg;
    aSrc[p] = A  + (size_t)(bm + row) * K + csw;
    bSrc[p] = BT + (size_t)(bn + row) * K + csw;
  }
  f32x4 acc[4][4] = {};
  const int NT = K >> 6;
  #pragma unroll
  for (int p = 0; p < 4; ++p) glds16(aSrc[p], &As[0][(p * 4 + wid) * 512]);
  #pragma unroll
  for (int p = 0; p < 4; ++p) glds16(bSrc[p], &Bs[0][(p * 4 + wid) * 512]);
  for (int t = 0; t < NT; ++t) {
    const int cur = t & 1;
    if (t + 1 < NT) {
      const int k0 = (t + 1) << 6;
      #pragma unroll
      for (int p = 0; p < 4; ++p) glds16(aSrc[p] + k0, &As[cur ^ 1][(p * 4 + wid) * 512]);
      #pragma unroll
      for (int p = 0; p < 4; ++p) glds16(bSrc[p] + k0, &Bs[cur ^ 1][(p * 4 + wid) * 512]);
      asm volatile("s_waitcnt vmcnt(8)" ::: "memory");
    } else {
      asm volatile("s_waitcnt vmcnt(0)" ::: "memory");
    }
    __builtin_amdgcn_s_barrier();
    __builtin_amdgcn_sched_barrier(0);
    const unsigned short* ab = &As[cur][0];
    const unsigned short* bb = &Bs[cur][0];
    #pragma unroll
    for (int ks = 0; ks < 2; ++ks) {
      bf16x8 af[4], bf[4];
      #pragma unroll
      for (int i = 0; i < 4; ++i) {
        int ra = wm + i * 16 + l16;
        int rb = wn + i * 16 + l16;
        int ch = ((ks * 4 + g4) ^ (l16 & 7)) * 8;
        af[i] = *(const bf16x8*)&ab[ra * 64 + ch];
        bf[i] = *(const bf16x8*)&bb[rb * 64 + ch];
      }
      #pragma unroll
      for (int mi = 0; mi < 4; ++mi)
        #pragma unroll
        for (int ni = 0; ni < 4; ++ni)
          acc[mi][ni] = __builtin_amdgcn_mfma_f32_16x16x32_bf16(af[mi], bf[ni], acc[mi][ni], 0, 0, 0);
    }
    __builtin_amdgcn_sched_barrier(0);
    __builtin_amdgcn_s_barrier();
  }
  const int r4 = g4 * 4;
  #pragma unroll
  for (int mi = 0; mi < 4; ++mi)
    #pragma unroll
    for (int ni = 0; ni < 4; ++ni)
      #pragma unroll
      for (int r = 0; r < 4; ++r) {
        int row = bm + wm + mi * 16 + r4 + r;
        int col = bn + wn + ni * 16 + l16;
        float v = acc[mi][ni][r];
        if (resid) v += resid[(size_t)row * N + col];
        C[(size_t)row * N + col] = v;
      }
}

// ---------------------------------------------------------------------------
// Expert-batched MoE GEMM, 128x256 tile, 256 threads (4 waves of 128x64).
// Work index: w = e*128 + bm4*8 + bn3  (bn FASTEST -> working blocks are a
// contiguous idx prefix per expert -> spread across all 32 CUs/XCD).
// Grid 1024 (16bm x 8bn x 8e), XCD-swizzled -> one expert per XCD.
// Counted-vmcnt dbuf (12 loads/thread/tile), 96KB LDS.
// ---------------------------------------------------------------------------
__global__ __launch_bounds__(256) void gemm_moe_128x256(
    const unsigned short* __restrict__ A, const unsigned short* __restrict__ BTall,
    float* __restrict__ C,
    const int* __restrict__ counts, const int* __restrict__ offsets,
    const int* __restrict__ pair_token, const unsigned short* __restrict__ zbuf,
    int gather, int K, int N)
{
  const int w = xcd_swz(blockIdx.x, gridDim.x);
  const int e = w >> 7;
  const int cnt = counts[e];
  const int bm = ((w >> 3) & 15) * 128;
  if (bm >= cnt) return;
  const int base = offsets[e];
  const int bn = (w & 7) * 256;
  __shared__ unsigned short As[2][128 * 64];
  __shared__ unsigned short Bs[2][256 * 64];
  __shared__ int rowmap[128];
  const int tid = threadIdx.x, lane = tid & 63, wid = tid >> 6;
  const int l16 = lane & 15, g4 = lane >> 4;
  const int rseg = lane >> 3;
  const int csw  = ((lane & 7) ^ rseg) * 8;
  if (tid < 128) {
    int lr = bm + tid;
    rowmap[tid] = (lr < cnt) ? (gather ? pair_token[base + lr] : base + lr) : -1;
  }
  __syncthreads();
  const unsigned short* BT = BTall + (size_t)e * N * K;
  const unsigned short* aSrc[4];
  const unsigned short* bSrc[8];
  int aOk[4];
  #pragma unroll
  for (int p = 0; p < 4; ++p) {
    int row = p * 32 + wid * 8 + rseg;
    int tok = rowmap[row];
    aOk[p] = (tok >= 0);
    aSrc[p] = aOk[p] ? (A + (size_t)tok * K + csw) : (zbuf + csw);
  }
  #pragma unroll
  for (int p = 0; p < 8; ++p) {
    int row = p * 32 + wid * 8 + rseg;
    bSrc[p] = BT + (size_t)(bn + row) * K + csw;
  }
  f32x4 acc[8][4] = {};
  const int NT = K >> 6;
  // prologue: stage tile 0 -> buf 0
  #pragma unroll
  for (int p = 0; p < 4; ++p) glds16(aSrc[p], &As[0][(p * 32 + wid * 8) * 64]);
  #pragma unroll
  for (int p = 0; p < 8; ++p) glds16(bSrc[p], &Bs[0][(p * 32 + wid * 8) * 64]);
  for (int t = 0; t < NT; ++t) {
    const int cur = t & 1;
    if (t + 1 < NT) {
      const int k0 = (t + 1) << 6;
      #pragma unroll
      for (int p = 0; p < 4; ++p)
        glds16(aSrc[p] + (aOk[p] ? k0 : 0), &As[cur ^ 1][(p * 32 + wid * 8) * 64]);
      #pragma unroll
      for (int p = 0; p < 8; ++p)
        glds16(bSrc[p] + k0, &Bs[cur ^ 1][(p * 32 + wid * 8) * 64]);
      asm volatile("s_waitcnt vmcnt(12)" ::: "memory");  // own tile-t done
    } else {
      asm volatile("s_waitcnt vmcnt(0)" ::: "memory");
    }
    __builtin_amdgcn_s_barrier();
    __builtin_amdgcn_sched_barrier(0);
    const unsigned short* ab = &As[cur][0];
    const unsigned short* bb = &Bs[cur][0];
    #pragma unroll
    for (int ks = 0; ks < 2; ++ks) {
      const int ch = ((ks * 4 + g4) ^ (l16 & 7)) * 8;
      bf16x8 bf[4];
      #pragma unroll
      for (int ni = 0; ni < 4; ++ni)
        bf[ni] = *(const bf16x8*)&bb[(wid * 64 + ni * 16 + l16) * 64 + ch];
      #pragma unroll
      for (int mi = 0; mi < 8; ++mi) {
        bf16x8 af = *(const bf16x8*)&ab[(mi * 16 + l16) * 64 + ch];
        #pragma unroll
        for (int ni = 0; ni < 4; ++ni)
          acc[mi][ni] = __builtin_amdgcn_mfma_f32_16x16x32_bf16(af, bf[ni], acc[mi][ni], 0, 0, 0);
      }
    }
    __builtin_amdgcn_sched_barrier(0);
    __builtin_amdgcn_s_barrier();
  }
  const int r4 = g4 * 4;
  #pragma unroll
  for (int mi = 0; mi < 8; ++mi)
    #pragma unroll
    for (int ni = 0; ni < 4; ++ni)
      #pragma unroll
      for (int r = 0; r < 4; ++r) {
        int lrow = bm + mi * 16 + r4 + r;
        int col  = bn + wid * 64 + ni * 16 + l16;
        if (lrow < cnt)
          C[(size_t)(base + lrow) * N + col] = acc[mi][ni][r];
      }
}

// ---------------------------------------------------------------------------
// RMSNorm over D=2048, f32 in -> bf16 out (+ optional exact f32 out).
// ---------------------------------------------------------------------------
__global__ __launch_bounds__(256) void rmsnorm_rows(
    const float* __restrict__ in, const float* __restrict__ w,
    unsigned short* __restrict__ out, float* __restrict__ out32)
{
  const int row = blockIdx.x;
  const int tid = threadIdx.x;
  const float* x = in + (size_t)row * 2048;
  float4 a = *(const float4*)&x[tid * 8];
  float4 b = *(const float4*)&x[tid * 8 + 4];
  float s = a.x*a.x + a.y*a.y + a.z*a.z + a.w*a.w
          + b.x*b.x + b.y*b.y + b.z*b.z + b.w*b.w;
  #pragma unroll
  for (int off = 1; off < 64; off <<= 1) s += __shfl_xor(s, off);
  __shared__ float red[4];
  if ((tid & 63) == 0) red[tid >> 6] = s;
  __syncthreads();
  float inv = rsqrtf((red[0] + red[1] + red[2] + red[3]) * (1.f / 2048.f) + 1e-6f);
  float4 wa = *(const float4*)&w[tid * 8];
  float4 wb = *(const float4*)&w[tid * 8 + 4];
  float y[8] = {a.x * inv * wa.x, a.y * inv * wa.y, a.z * inv * wa.z, a.w * inv * wa.w,
                b.x * inv * wb.x, b.y * inv * wb.y, b.z * inv * wb.z, b.w * inv * wb.w};
  unsigned short* o = out + (size_t)row * 2048 + tid * 8;
  #pragma unroll
  for (int j = 0; j < 8; ++j) o[j] = f2bf(y[j]);
  if (out32) {
    float* o32 = out32 + (size_t)row * 2048 + tid * 8;
    *(float4*)&o32[0] = make_float4(y[0], y[1], y[2], y[3]);
    *(float4*)&o32[4] = make_float4(y[4], y[5], y[6], y[7]);
  }
}

__global__ __launch_bounds__(256) void f32_to_bf16_k(
    const float* __restrict__ in, unsigned short* __restrict__ out, int n)
{
  int i = (blockIdx.x * 256 + threadIdx.x) * 4;
  if (i + 3 < n) {
    float4 v = *(const float4*)&in[i];
    out[i + 0] = f2bf(v.x); out[i + 1] = f2bf(v.y);
    out[i + 2] = f2bf(v.z); out[i + 3] = f2bf(v.w);
  }
}

// ---------------------------------------------------------------------------
// Per-(b,s,h) head RMSNorm + RoPE, relayout to (B, NH, seq_total, 128) bf16.
// ---------------------------------------------------------------------------
__global__ __launch_bounds__(256) void qk_norm_rope(
    const float* __restrict__ raw, int ld, const float* __restrict__ nw,
    const float* __restrict__ cosT, const float* __restrict__ sinT,
    unsigned short* __restrict__ out,
    int S, int NH, int seq_total, int s_off, float premul)
{
  int rowid = blockIdx.x * 4 + (threadIdx.x >> 6);
  int lane  = threadIdx.x & 63;
  int b = rowid / (S * NH);
  int rem = rowid % (S * NH);
  int s = rem / NH, h = rem % NH;
  const float* src = raw + (size_t)(b * S + s) * ld + h * 128;
  float2 xv = *(const float2*)&src[lane * 2];
  float ss = xv.x * xv.x + xv.y * xv.y;
  #pragma unroll
  for (int off = 1; off < 64; off <<= 1) ss += __shfl_xor(ss, off);
  float inv = rsqrtf(ss * (1.f / 128.f) + 1e-6f);
  float yr = xv.x * inv * nw[lane * 2];
  float yi = xv.y * inv * nw[lane * 2 + 1];
  float c  = cosT[s * 64 + lane], sn = sinT[s * 64 + lane];
  float orr = (yr * c - yi * sn) * premul;
  float oi  = (yr * sn + yi * c) * premul;
  unsigned short* dst = out + ((size_t)(b * NH + h) * seq_total + (s + s_off)) * 128;
  dst[lane * 2]     = f2bf(orr);
  dst[lane * 2 + 1] = f2bf(oi);
}

__global__ __launch_bounds__(256) void v_relayout(
    const float* __restrict__ raw, int ld, unsigned short* __restrict__ out,
    int S, int NH, int seq_total, int s_off)
{
  int rowid = blockIdx.x * 4 + (threadIdx.x >> 6);
  int lane  = threadIdx.x & 63;
  int b = rowid / (S * NH);
  int rem = rowid % (S * NH);
  int s = rem / NH, h = rem % NH;
  const float* src = raw + (size_t)(b * S + s) * ld + h * 128;
  float2 xv = *(const float2*)&src[lane * 2];
  unsigned short* dst = out + ((size_t)(b * NH + h) * seq_total + (s + s_off)) * 128;
  dst[lane * 2]     = f2bf(xv.x);
  dst[lane * 2 + 1] = f2bf(xv.y);
}

// ---------------------------------------------------------------------------
// Flash attention (unchanged from r8): XOR-swizzled LDS + async dbuf reg
// staging, 64 q-rows/block, Sk tiles of 64.
// ---------------------------------------------------------------------------
__global__ __launch_bounds__(256) void attn_kernel(
    const unsigned short* __restrict__ q,
    const unsigned short* __restrict__ kbuf,
    const unsigned short* __restrict__ vbuf,
    unsigned short* __restrict__ o)
{
  const int SK = 1536;
  const int w = xcd_swz(blockIdx.x, gridDim.x);
  const int bh = w >> 4;
  const int b = bh >> 4, h = bh & 15, kvh = h >> 2;
  const int q0 = (w & 15) * 64;
  const int tid = threadIdx.x, lane = tid & 63, wid = tid >> 6;
  const int l16 = lane & 15, kb = (lane >> 4) * 8, r4 = (lane >> 4) * 4;
  __shared__ unsigned short KsL[64 * 128];
  __shared__ unsigned short VTL[128 * 64];
  __shared__ unsigned short PsL[4 * 16 * 64];
  const int sr0 = tid >> 4;
  const int scc = (tid & 15) * 8;

  const unsigned short* qrow =
      q + ((size_t)(b * 16 + h) * 1024 + q0 + wid * 16 + l16) * 128;
  bf16x8 qf[4];
  #pragma unroll
  for (int ks = 0; ks < 4; ++ks) qf[ks] = *(const bf16x8*)&qrow[ks * 32 + kb];
  float mrow[4] = {-1e30f, -1e30f, -1e30f, -1e30f};
  float lrow[4] = {0.f, 0.f, 0.f, 0.f};
  f32x4 oacc[8] = {};
  const unsigned short* kb_base = kbuf + (size_t)(b * 4 + kvh) * SK * 128;
  const unsigned short* vb_base = vbuf + (size_t)(b * 4 + kvh) * SK * 128;

  u16x8 k0[4], v0[4], k1[4], v1[4];

#define ATT_LOAD(kr, vr, kt1)                                                 \
  {                                                                           \
    _Pragma("unroll")                                                         \
    for (int i = 0; i < 4; ++i) {                                             \
      kr[i] = *(const u16x8*)&kb_base[(size_t)((kt1) + sr0 + 16 * i) * 128 + scc]; \
      vr[i] = *(const u16x8*)&vb_base[(size_t)((kt1) + sr0 + 16 * i) * 128 + scc]; \
    }                                                                         \
  }

#define ATT_STAGE(kr, vr)                                                     \
  {                                                                           \
    _Pragma("unroll")                                                         \
    for (int i = 0; i < 4; ++i) {                                             \
      int rr = sr0 + 16 * i;                                                  \
      *(u16x8*)&KsL[rr * 128 + (((scc >> 3) ^ (rr & 7)) << 3)] = kr[i];       \
      _Pragma("unroll")                                                       \
      for (int j = 0; j < 8; ++j)                                             \
        VTL[(scc + j) * 64 + ((((rr >> 3) ^ ((scc + j) >> 3)) & 7) << 3) + (rr & 7)] = vr[i][j]; \
    }                                                                         \
  }

  auto compute = [&]() {
    f32x4 sacc[4] = {};
    #pragma unroll
    for (int ks = 0; ks < 4; ++ks) {
      #pragma unroll
      for (int ni = 0; ni < 4; ++ni) {
        int rr = ni * 16 + l16;
        bf16x8 kf = *(const bf16x8*)
            &KsL[rr * 128 + ((((ks * 32 + kb) >> 3) ^ (rr & 7)) << 3)];
        sacc[ni] = __builtin_amdgcn_mfma_f32_16x16x32_bf16(qf[ks], kf, sacc[ni], 0, 0, 0);
      }
    }
    float pv[4][4], alpha[4];
    #pragma unroll
    for (int r = 0; r < 4; ++r) {
      float tm = fmaxf(fmaxf(sacc[0][r], sacc[1][r]), fmaxf(sacc[2][r], sacc[3][r]));
      #pragma unroll
      for (int off = 1; off < 16; off <<= 1) tm = fmaxf(tm, __shfl_xor(tm, off));
      float mn = fmaxf(mrow[r], tm);
      alpha[r] = __expf(mrow[r] - mn);
      float s = 0.f;
      #pragma unroll
      for (int ni = 0; ni < 4; ++ni) {
        float p = __expf(sacc[ni][r] - mn);
        pv[ni][r] = p; s += p;
      }
      #pragma unroll
      for (int off = 1; off < 16; off <<= 1) s += __shfl_xor(s, off);
      lrow[r] = lrow[r] * alpha[r] + s;
      mrow[r] = mn;
    }
    #pragma unroll
    for (int ni = 0; ni < 8; ++ni)
      #pragma unroll
      for (int r = 0; r < 4; ++r) oacc[ni][r] *= alpha[r];
    #pragma unroll
    for (int ni = 0; ni < 4; ++ni)
      #pragma unroll
      for (int r = 0; r < 4; ++r) {
        int row = r4 + r, col = ni * 16 + l16;
        PsL[wid * 1024 + row * 64 + ((((col >> 3) ^ (row & 7)) & 7) << 3) + (col & 7)]
            = f2bf(pv[ni][r]);
      }
    asm volatile("s_waitcnt lgkmcnt(0)" ::: "memory");
    __builtin_amdgcn_sched_barrier(0);
    #pragma unroll
    for (int ks = 0; ks < 2; ++ks) {
      bf16x8 pf = *(const bf16x8*)
          &PsL[wid * 1024 + l16 * 64 + ((((ks * 32 + kb) >> 3) ^ (l16 & 7)) << 3)];
      #pragma unroll
      for (int ni = 0; ni < 8; ++ni) {
        int d = ni * 16 + l16;
        bf16x8 vf = *(const bf16x8*)
            &VTL[d * 64 + ((((ks * 32 + kb) >> 3) ^ ((d >> 3) & 7)) << 3)];
        oacc[ni] = __builtin_amdgcn_mfma_f32_16x16x32_bf16(pf, vf, oacc[ni], 0, 0, 0);
      }
    }
  };

  ATT_LOAD(k0, v0, 0);
  for (int t = 0; t < 24; t += 2) {
    ATT_STAGE(k0, v0);
    ATT_LOAD(k1, v1, (t + 1) * 64);
    asm volatile("s_waitcnt lgkmcnt(0)" ::: "memory");
    __builtin_amdgcn_s_barrier();
    __builtin_amdgcn_sched_barrier(0);
    compute();
    __builtin_amdgcn_sched_barrier(0);
    __builtin_amdgcn_s_barrier();
    ATT_STAGE(k1, v1);
    if (t + 2 < 24) ATT_LOAD(k0, v0, (t + 2) * 64);
    asm volatile("s_waitcnt lgkmcnt(0)" ::: "memory");
    __builtin_amdgcn_s_barrier();
    __builtin_amdgcn_sched_barrier(0);
    compute();
    __builtin_amdgcn_sched_barrier(0);
    __builtin_amdgcn_s_barrier();
  }
#undef ATT_LOAD
#undef ATT_STAGE

  #pragma unroll
  for (int ni = 0; ni < 8; ++ni)
    #pragma unroll
    for (int r = 0; r < 4; ++r) {
      float val = oacc[ni][r] / lrow[r];
      size_t row = (size_t)b * 1024 + q0 + wid * 16 + r4 + r;
      o[row * 2048 + h * 128 + ni * 16 + l16] = f2bf(val);
    }
}

// ---------------------------------------------------------------------------
// Router: one wave per token, f32 input (exact), f32 accumulate.
// ---------------------------------------------------------------------------
__global__ __launch_bounds__(64) void router_kernel(
    const float* __restrict__ xt32, const float* __restrict__ rw,
    int* __restrict__ topi, float* __restrict__ topw, int* __restrict__ counts)
{
  int t = blockIdx.x, lane = threadIdx.x;
  float acc[8] = {};
  const float* x = xt32 + (size_t)t * 2048;
  for (int d0 = lane * 4; d0 < 2048; d0 += 256) {
    float4 xv = *(const float4*)&x[d0];
    float xa[4] = {xv.x, xv.y, xv.z, xv.w};
    #pragma unroll
    for (int j = 0; j < 4; ++j) {
      const float4 r0 = *(const float4*)&rw[(d0 + j) * 8];
      const float4 r1 = *(const float4*)&rw[(d0 + j) * 8 + 4];
      acc[0] += xa[j] * r0.x; acc[1] += xa[j] * r0.y;
      acc[2] += xa[j] * r0.z; acc[3] += xa[j] * r0.w;
      acc[4] += xa[j] * r1.x; acc[5] += xa[j] * r1.y;
      acc[6] += xa[j] * r1.z; acc[7] += xa[j] * r1.w;
    }
  }
  #pragma unroll
  for (int e = 0; e < 8; ++e)
    #pragma unroll
    for (int off = 1; off < 64; off <<= 1) acc[e] += __shfl_xor(acc[e], off);
  if (lane == 0) {
    float v0 = acc[0]; int e0 = 0;
    #pragma unroll
    for (int e = 1; e < 8; ++e) if (acc[e] > v0) { v0 = acc[e]; e0 = e; }
    float v1 = -1e30f; int e1 = 0;
    #pragma unroll
    for (int e = 0; e < 8; ++e) if (e != e0 && acc[e] > v1) { v1 = acc[e]; e1 = e; }
    float x1 = expf(v1 - v0);
    float w0 = 1.f / (1.f + x1);
    float w1 = x1 / (1.f + x1);
    topi[2 * t] = e0; topi[2 * t + 1] = e1;
    topw[2 * t] = w0; topw[2 * t + 1] = w1;
    atomicAdd(&counts[e0], 1);
    atomicAdd(&counts[e1], 1);
  }
}

__global__ void scan_offsets(const int* __restrict__ counts, int* __restrict__ offsets)
{
  if (threadIdx.x == 0 && blockIdx.x == 0) {
    int a = 0;
    for (int e = 0; e < 8; ++e) { offsets[e] = a; a += counts[e]; }
    offsets[8] = a;
  }
}

__global__ __launch_bounds__(256) void scatter_pairs(
    const int* __restrict__ topi, const int* __restrict__ offsets,
    int* __restrict__ fill, int* __restrict__ pair_token, int* __restrict__ token_slot)
{
  int t = blockIdx.x * 256 + threadIdx.x;
  if (t >= 2048) return;
  #pragma unroll
  for (int k = 0; k < 2; ++k) {
    int e = topi[2 * t + k];
    int slot = offsets[e] + atomicAdd(&fill[e], 1);
    pair_token[slot] = t;
    token_slot[2 * t + k] = slot;
  }
}

__global__ __launch_bounds__(256) void act_silu(
    const float* __restrict__ gu, unsigned short* __restrict__ act)
{
  int p = blockIdx.x;
  int c = threadIdx.x * 4;
  float4 g = *(const float4*)&gu[(size_t)p * 2048 + c];
  float4 u = *(const float4*)&gu[(size_t)p * 2048 + 1024 + c];
  float gg[4] = {g.x, g.y, g.z, g.w};
  float uu[4] = {u.x, u.y, u.z, u.w};
  #pragma unroll
  for (int j = 0; j < 4; ++j) {
    float a = gg[j] / (1.f + __expf(-gg[j])) * uu[j];
    act[(size_t)p * 1024 + c + j] = f2bf(a);
  }
}

__global__ __launch_bounds__(256) void moe_combine(
    float* __restrict__ out, const float* __restrict__ eo,
    const int* __restrict__ token_slot, const float* __restrict__ topw)
{
  int t = blockIdx.x;
  int c = threadIdx.x * 8;
  int s0 = token_slot[2 * t], s1 = token_slot[2 * t + 1];
  float w0 = topw[2 * t], w1 = topw[2 * t + 1];
  #pragma unroll
  for (int j0 = 0; j0 < 8; j0 += 4) {
    float4 a = *(const float4*)&eo[(size_t)s0 * 2048 + c + j0];
    float4 b = *(const float4*)&eo[(size_t)s1 * 2048 + c + j0];
    float4 v = *(const float4*)&out[(size_t)t * 2048 + c + j0];
    v.x += w0 * a.x + w1 * b.x;
    v.y += w0 * a.y + w1 * b.y;
    v.z += w0 * a.z + w1 * b.z;
    v.w += w0 * a.w + w1 * b.w;
    *(float4*)&out[(size_t)t * 2048 + c + j0] = v;
  }
}

// ---------------------------------------------------------------------------
extern "C" void kernel_launch(void* const* d_in, const int* in_sizes, int n_in,
                              void* d_out, int out_size, void* d_ws, size_t ws_size,
                              hipStream_t stream)
{
  const float* hidden  = (const float*)d_in[0];
  const float* enc     = (const float*)d_in[1];
  const float* img_cos = (const float*)d_in[2];
  const float* img_sin = (const float*)d_in[3];
  const float* txt_cos = (const float*)d_in[4];
  const float* txt_sin = (const float*)d_in[5];
  const float* norm1_w = (const float*)d_in[6];
  const float* norm2_w = (const float*)d_in[7];
  const float* wq      = (const float*)d_in[8];
  const float* wk      = (const float*)d_in[9];
  const float* wv      = (const float*)d_in[10];
  const float* wk_txt  = (const float*)d_in[11];
  const float* wv_txt  = (const float*)d_in[12];
  const float* wo      = (const float*)d_in[13];
  const float* q_norm_w       = (const float*)d_in[14];
  const float* k_norm_w       = (const float*)d_in[15];
  const float* added_k_norm_w = (const float*)d_in[16];
  const float* router_w       = (const float*)d_in[17];
  const float* gate_up_proj   = (const float*)d_in[18];
  const float* down_proj      = (const float*)d_in[19];
  float* out = (float*)d_out;

  char* ws = (char*)d_ws;
  size_t off = 0;
  auto alloc = [&](size_t bytes) {
    void* p = ws + off;
    off += (bytes + 255) & ~(size_t)255;
    return p;
  };
  // --- bf16 transposed weights ---
  unsigned short* wqkvT  = (unsigned short*)alloc(3072ULL * 2048 * 2); // q|k|v rows
  unsigned short* wkvtT  = (unsigned short*)alloc(1024ULL * 2048 * 2); // k_txt|v_txt
  unsigned short* woT    = (unsigned short*)alloc(2048ULL * 2048 * 2);
  unsigned short* gupT   = (unsigned short*)alloc(8ULL * 2048 * 2048 * 2);
  unsigned short* dnT    = (unsigned short*)alloc(8ULL * 2048 * 1024 * 2);
  // --- activations ---
  unsigned short* x_bf   = (unsigned short*)alloc(2048ULL * 2048 * 2);
  unsigned short* enc_bf = (unsigned short*)alloc(1024ULL * 2048 * 2);
  float* qkvC = (float*)alloc(4096ULL * 2048 * 4); // [2048][3072] early; gu [4096][2048] late
  float* gu   = qkvC;                              // alias (disjoint lifetimes)
  float* kvtC = (float*)alloc(1024ULL * 1024 * 4); // [1024][1024] k_txt|v_txt
  unsigned short* qb   = (unsigned short*)alloc(2048ULL * 2048 * 2);
  unsigned short* kbuf = (unsigned short*)alloc(2ULL * 4 * 1536 * 128 * 2);
  unsigned short* vbuf = (unsigned short*)alloc(2ULL * 4 * 1536 * 128 * 2);
  unsigned short* obuf = (unsigned short*)alloc(2048ULL * 2048 * 2);
  unsigned short* act  = obuf;                     // alias (obuf dead after wo GEMM)
  unsigned short* xt   = (unsigned short*)alloc(2048ULL * 2048 * 2);
  float* xt32 = (float*)alloc(2048ULL * 2048 * 4);
  int*   ctrl  = (int*)alloc(64 * sizeof(int));    // counts[8] fill[8] offsets[9]
  int*   topi  = (int*)alloc(4096 * 4);
  float* topw  = (float*)alloc(4096 * 4);
  int*   tslot = (int*)alloc(4096 * 4);
  int*   ptok  = (int*)alloc(4096 * 4);
  unsigned short* zbuf = (unsigned short*)alloc(256);
  int* counts = ctrl, * fill = ctrl + 8, * offsets = ctrl + 16;

  hipMemsetAsync(ctrl, 0, 64, stream);
  hipMemsetAsync(zbuf, 0, 256, stream);

  const float scale = 0.08838834764831845f;  // 1/sqrt(128)

  // --- weight preprocessing: f32 [K][N] -> bf16 [N][K] ---
  convert_w<<<dim3(32, 32, 1), 256, 0, stream>>>(wq,     wqkvT,                    2048, 2048);
  convert_w<<<dim3(32,  8, 1), 256, 0, stream>>>(wk,     wqkvT + 2048ULL * 2048,   2048, 512);
  convert_w<<<dim3(32,  8, 1), 256, 0, stream>>>(wv,     wqkvT + 2560ULL * 2048,   2048, 512);
  convert_w<<<dim3(32,  8, 1), 256, 0, stream>>>(wk_txt, wkvtT,                    2048, 512);
  convert_w<<<dim3(32,  8, 1), 256, 0, stream>>>(wv_txt, wkvtT + 512ULL * 2048,    2048, 512);
  convert_w<<<dim3(32, 32, 1), 256, 0, stream>>>(wo,     woT,                      2048, 2048);
  convert_w<<<dim3(32, 32, 8), 256, 0, stream>>>(gate_up_proj, gupT,               2048, 2048);
  convert_w<<<dim3(16, 32, 8), 256, 0, stream>>>(down_proj,    dnT,                1024, 2048);

  rmsnorm_rows<<<2048, 256, 0, stream>>>(hidden, norm1_w, x_bf, nullptr);
  f32_to_bf16_k<<<2048, 256, 0, stream>>>(enc, enc_bf, 1024 * 2048);

  // fused qkv projection: [2048][2048] @ [3072][2048]^T -> [2048][3072]
  gemm_bb<<<384, 256, 0, stream>>>(x_bf, wqkvT, qkvC, nullptr, 2048, 3072, 2048);
  // fused k/v txt projection: [1024][2048] @ [1024][2048]^T -> [1024][1024]
  gemm_bb<<<64, 256, 0, stream>>>(enc_bf, wkvtT, kvtC, nullptr, 1024, 1024, 2048);

  qk_norm_rope<<<8192, 256, 0, stream>>>(qkvC, 3072, q_norm_w, img_cos, img_sin, qb,
                                         1024, 16, 1024, 0, scale);
  qk_norm_rope<<<2048, 256, 0, stream>>>(qkvC + 2048, 3072, k_norm_w, img_cos, img_sin, kbuf,
                                         1024, 4, 1536, 0, 1.0f);
  qk_norm_rope<<<1024, 256, 0, stream>>>(kvtC, 1024, added_k_norm_w, txt_cos, txt_sin, kbuf,
                                         512, 4, 1536, 1024, 1.0f);
  v_relayout<<<2048, 256, 0, stream>>>(qkvC + 2560, 3072, vbuf, 1024, 4, 1536, 0);
  v_relayout<<<1024, 256, 0, stream>>>(kvtC + 512, 1024, vbuf, 512, 4, 1536, 1024);

  attn_kernel<<<512, 256, 0, stream>>>(qb, kbuf, vbuf, obuf);

  gemm_bb<<<256, 256, 0, stream>>>(obuf, woT, out, hidden, 2048, 2048, 2048);

  rmsnorm_rows<<<2048, 256, 0, stream>>>(out, norm2_w, xt, xt32);
  router_kernel<<<2048, 64, 0, stream>>>(xt32, router_w, topi, topw, counts);
  scan_offsets<<<1, 64, 0, stream>>>(counts, offsets);
  scatter_pairs<<<8, 256, 0, stream>>>(topi, offsets, fill, ptok, tslot);

  gemm_moe_128x256<<<1024, 256, 0, stream>>>(xt, gupT, gu,
                                             counts, offsets, ptok, zbuf, 1, 2048, 2048);
  act_silu<<<4096, 256, 0, stream>>>(gu, act);
  gemm_moe_128x256<<<1024, 256, 0, stream>>>(act, dnT, gu,
                                             counts, offsets, ptok, zbuf, 0, 1024, 2048);
  moe_combine<<<2048, 256, 0, stream>>>(out, gu, tslot, topw);
}

// Round 11
// 630.100 us; speedup vs baseline: 1.0368x; 1.0368x over previous
//
#include <hip/hip_runtime.h>

// ---------------------------------------------------------------------------
// NucleusMoEImageTransformerBlock round 11.
// B=2 SI=1024 ST=512 D=2048 H=16 KV=4 HD=128 E=8 F=1024 TOPK=2
// Round-11: MoE GEMM = 256x256 tile + split-K=2 (deterministic two-partial
// reduction, no atomics). Model fit from r8/r9/r10: time ~ staged_traffic /
// (active_CU_fraction * 5.2 TB/s). Split-K keeps r9's low traffic (256MB)
// while doubling coverage to 1 block/CU (256 working blocks, 32/XCD
// contiguous). gu0/gu1 partials summed in act_silu; eo0/eo1 in moe_combine.
// Everything else unchanged from r9.
// ---------------------------------------------------------------------------

typedef __attribute__((ext_vector_type(8))) __bf16 bf16x8;
typedef __attribute__((ext_vector_type(8))) unsigned short u16x8;
typedef __attribute__((ext_vector_type(4))) float f32x4;

__device__ __forceinline__ unsigned short f2bf(float x) {
  unsigned u = __builtin_bit_cast(unsigned, x);
  u += 0x7fffu + ((u >> 16) & 1u);        // RNE
  return (unsigned short)(u >> 16);
}
__device__ __forceinline__ float bf2f(unsigned short b) {
  return __builtin_bit_cast(float, ((unsigned)b) << 16);
}

__device__ __forceinline__ void glds16(const unsigned short* g, unsigned short* l) {
  __builtin_amdgcn_global_load_lds(
      (const __attribute__((address_space(1))) void*)g,
      (__attribute__((address_space(3))) void*)l, 16, 0, 0);
}

// m204 bijective XCD chunk swizzle.
__device__ __forceinline__ int xcd_swz(int orig, int nwg) {
  int q = nwg >> 3, r = nwg & 7;
  int xcd = orig & 7, idx = orig >> 3;
  int base = (xcd < r) ? xcd * (q + 1) : r * (q + 1) + (xcd - r) * q;
  return base + idx;
}

// ---------------------------------------------------------------------------
// Weight convert+transpose: W f32 [K][N] -> WT bf16 [N][K].
// ---------------------------------------------------------------------------
__global__ __launch_bounds__(256) void convert_w(
    const float* __restrict__ W, unsigned short* __restrict__ WT,
    int K, int N)
{
  __shared__ unsigned short T[64][66];
  const float* Wz = W + (size_t)blockIdx.z * K * N;
  unsigned short* WTz = WT + (size_t)blockIdx.z * K * N;
  const int k0 = blockIdx.x * 64, n0 = blockIdx.y * 64;
  const int tid = threadIdx.x;
  #pragma unroll
  for (int i = tid; i < 64 * 16; i += 256) {
    int k = i >> 4, n4 = (i & 15) * 4;
    float4 v = *(const float4*)&Wz[(size_t)(k0 + k) * N + n0 + n4];
    T[n4 + 0][k] = f2bf(v.x);
    T[n4 + 1][k] = f2bf(v.y);
    T[n4 + 2][k] = f2bf(v.z);
    T[n4 + 3][k] = f2bf(v.w);
  }
  __syncthreads();
  #pragma unroll
  for (int i = tid; i < 64 * 8; i += 256) {
    int n = i >> 3, k8 = (i & 7) * 8;
    *(u16x8*)&WTz[(size_t)(n0 + n) * K + k0 + k8] = *(const u16x8*)&T[n][k8];
  }
}

// ---------------------------------------------------------------------------
// Dense GEMM: C[M,N] = A[M,K] @ BT[N,K]^T (+resid). bf16 in, f32 out.
// 128x128 tile, counted-vmcnt dbuf pipeline (unchanged from r8).
// ---------------------------------------------------------------------------
__global__ __launch_bounds__(256) void gemm_bb(
    const unsigned short* __restrict__ A, const unsigned short* __restrict__ BT,
    float* __restrict__ C, const float* __restrict__ resid,
    int M, int N, int K)
{
  __shared__ unsigned short As[2][128 * 64];
  __shared__ unsigned short Bs[2][128 * 64];
  const int mb = M >> 7;
  const int w = xcd_swz(blockIdx.x, gridDim.x);
  const int bm = (w % mb) * 128, bn = (w / mb) * 128;
  const int tid = threadIdx.x, lane = tid & 63, wid = tid >> 6;
  const int wm = (wid >> 1) * 64, wn = (wid & 1) * 64;
  const int l16 = lane & 15, g4 = lane >> 4;
  const int rseg = lane >> 3;
  const int csw  = ((lane & 7) ^ rseg) * 8;
  const unsigned short* aSrc[4];
  const unsigned short* bSrc[4];
  #pragma unroll
  for (int p = 0; p < 4; ++p) {
    int row = (p * 4 + wid) * 8 + rseg;
    aSrc[p] = A  + (size_t)(bm + row) * K + csw;
    bSrc[p] = BT + (size_t)(bn + row) * K + csw;
  }
  f32x4 acc[4][4] = {};
  const int NT = K >> 6;
  #pragma unroll
  for (int p = 0; p < 4; ++p) glds16(aSrc[p], &As[0][(p * 4 + wid) * 512]);
  #pragma unroll
  for (int p = 0; p < 4; ++p) glds16(bSrc[p], &Bs[0][(p * 4 + wid) * 512]);
  for (int t = 0; t < NT; ++t) {
    const int cur = t & 1;
    if (t + 1 < NT) {
      const int k0 = (t + 1) << 6;
      #pragma unroll
      for (int p = 0; p < 4; ++p) glds16(aSrc[p] + k0, &As[cur ^ 1][(p * 4 + wid) * 512]);
      #pragma unroll
      for (int p = 0; p < 4; ++p) glds16(bSrc[p] + k0, &Bs[cur ^ 1][(p * 4 + wid) * 512]);
      asm volatile("s_waitcnt vmcnt(8)" ::: "memory");
    } else {
      asm volatile("s_waitcnt vmcnt(0)" ::: "memory");
    }
    __builtin_amdgcn_s_barrier();
    __builtin_amdgcn_sched_barrier(0);
    const unsigned short* ab = &As[cur][0];
    const unsigned short* bb = &Bs[cur][0];
    #pragma unroll
    for (int ks = 0; ks < 2; ++ks) {
      bf16x8 af[4], bf[4];
      #pragma unroll
      for (int i = 0; i < 4; ++i) {
        int ra = wm + i * 16 + l16;
        int rb = wn + i * 16 + l16;
        int ch = ((ks * 4 + g4) ^ (l16 & 7)) * 8;
        af[i] = *(const bf16x8*)&ab[ra * 64 + ch];
        bf[i] = *(const bf16x8*)&bb[rb * 64 + ch];
      }
      #pragma unroll
      for (int mi = 0; mi < 4; ++mi)
        #pragma unroll
        for (int ni = 0; ni < 4; ++ni)
          acc[mi][ni] = __builtin_amdgcn_mfma_f32_16x16x32_bf16(af[mi], bf[ni], acc[mi][ni], 0, 0, 0);
    }
    __builtin_amdgcn_sched_barrier(0);
    __builtin_amdgcn_s_barrier();
  }
  const int r4 = g4 * 4;
  #pragma unroll
  for (int mi = 0; mi < 4; ++mi)
    #pragma unroll
    for (int ni = 0; ni < 4; ++ni)
      #pragma unroll
      for (int r = 0; r < 4; ++r) {
        int row = bm + wm + mi * 16 + r4 + r;
        int col = bn + wn + ni * 16 + l16;
        float v = acc[mi][ni][r];
        if (resid) v += resid[(size_t)row * N + col];
        C[(size_t)row * N + col] = v;
      }
}

// ---------------------------------------------------------------------------
// Expert-batched MoE GEMM, 256x256 tile, split-K=2, 512 threads (8 waves as
// 2x4, each 128x64). Single-buffer 64KB LDS. Grid 512 = 4bm x 2kh x 8bn x 8e,
// XCD-swizzled -> one expert per XCD; working (bm<2,kh,bn) combos are the
// contiguous first 32 of each XCD's 64-chunk -> all 32 CUs/XCD covered.
// K-half kh computes A[:, kh*Kh : (kh+1)*Kh] @ B^T and writes partial C[kh].
// ---------------------------------------------------------------------------
__global__ __launch_bounds__(512, 1) void gemm_moe_256sk(
    const unsigned short* __restrict__ A, const unsigned short* __restrict__ BTall,
    float* __restrict__ C0, float* __restrict__ C1,
    const int* __restrict__ counts, const int* __restrict__ offsets,
    const int* __restrict__ pair_token, const unsigned short* __restrict__ zbuf,
    int gather, int K, int N)
{
  const int w = xcd_swz(blockIdx.x, gridDim.x);
  const int e = w >> 6;
  const int local = w & 63;
  const int bm = (local >> 4) * 256;       // 4 slots (1024-row headroom)
  const int kh = (local >> 3) & 1;
  const int bn = (local & 7) * 256;
  const int cnt = counts[e];
  if (bm >= cnt) return;
  const int base = offsets[e];
  const int Kh = K >> 1;
  float* __restrict__ C = kh ? C1 : C0;
  __shared__ unsigned short As[256 * 64];
  __shared__ unsigned short Bs[256 * 64];
  __shared__ int rowmap[256];
  const int tid = threadIdx.x, lane = tid & 63, wid = tid >> 6;
  const int wr = wid >> 2, wc = wid & 3;          // wave tile 128x64 at (wr,wc)
  const int l16 = lane & 15, g4 = lane >> 4;
  const int rseg = lane >> 3;
  const int csw  = ((lane & 7) ^ rseg) * 8;
  if (tid < 256) {
    int lr = bm + tid;
    rowmap[tid] = (lr < cnt) ? (gather ? pair_token[base + lr] : base + lr) : -1;
  }
  __syncthreads();
  const unsigned short* BT = BTall + (size_t)e * N * K;
  const unsigned short* aSrc[4];
  const unsigned short* bSrc[4];
  int aOk[4];
  #pragma unroll
  for (int p = 0; p < 4; ++p) {
    int row = (p * 8 + wid) * 8 + rseg;           // 0..255
    int tok = rowmap[row];
    aOk[p] = (tok >= 0);
    aSrc[p] = aOk[p] ? (A + (size_t)tok * K + kh * Kh + csw) : (zbuf + csw);
    bSrc[p] = BT + (size_t)(bn + row) * K + kh * Kh + csw;
  }
  f32x4 acc[8][4] = {};
  const int NT = Kh >> 6;
  for (int t = 0; t < NT; ++t) {
    const int k0 = t << 6;
    #pragma unroll
    for (int p = 0; p < 4; ++p)
      glds16(aSrc[p] + (aOk[p] ? k0 : 0), &As[(p * 8 + wid) * 512]);
    #pragma unroll
    for (int p = 0; p < 4; ++p)
      glds16(bSrc[p] + k0, &Bs[(p * 8 + wid) * 512]);
    __syncthreads();
    #pragma unroll
    for (int ks = 0; ks < 2; ++ks) {
      const int ch = ((ks * 4 + g4) ^ (l16 & 7)) * 8;
      bf16x8 bf[4];
      #pragma unroll
      for (int j = 0; j < 4; ++j)
        bf[j] = *(const bf16x8*)&Bs[(wc * 64 + j * 16 + l16) * 64 + ch];
      #pragma unroll
      for (int mi = 0; mi < 8; ++mi) {
        bf16x8 af = *(const bf16x8*)&As[(wr * 128 + mi * 16 + l16) * 64 + ch];
        #pragma unroll
        for (int ni = 0; ni < 4; ++ni)
          acc[mi][ni] = __builtin_amdgcn_mfma_f32_16x16x32_bf16(af, bf[ni], acc[mi][ni], 0, 0, 0);
      }
    }
    __syncthreads();
  }
  const int r4 = g4 * 4;
  #pragma unroll
  for (int mi = 0; mi < 8; ++mi)
    #pragma unroll
    for (int ni = 0; ni < 4; ++ni)
      #pragma unroll
      for (int r = 0; r < 4; ++r) {
        int lrow = bm + wr * 128 + mi * 16 + r4 + r;
        int col  = bn + wc * 64 + ni * 16 + l16;
        if (lrow < cnt)
          C[(size_t)(base + lrow) * N + col] = acc[mi][ni][r];
      }
}

// ---------------------------------------------------------------------------
// RMSNorm over D=2048, f32 in -> bf16 out (+ optional exact f32 out).
// ---------------------------------------------------------------------------
__global__ __launch_bounds__(256) void rmsnorm_rows(
    const float* __restrict__ in, const float* __restrict__ w,
    unsigned short* __restrict__ out, float* __restrict__ out32)
{
  const int row = blockIdx.x;
  const int tid = threadIdx.x;
  const float* x = in + (size_t)row * 2048;
  float4 a = *(const float4*)&x[tid * 8];
  float4 b = *(const float4*)&x[tid * 8 + 4];
  float s = a.x*a.x + a.y*a.y + a.z*a.z + a.w*a.w
          + b.x*b.x + b.y*b.y + b.z*b.z + b.w*b.w;
  #pragma unroll
  for (int off = 1; off < 64; off <<= 1) s += __shfl_xor(s, off);
  __shared__ float red[4];
  if ((tid & 63) == 0) red[tid >> 6] = s;
  __syncthreads();
  float inv = rsqrtf((red[0] + red[1] + red[2] + red[3]) * (1.f / 2048.f) + 1e-6f);
  float4 wa = *(const float4*)&w[tid * 8];
  float4 wb = *(const float4*)&w[tid * 8 + 4];
  float y[8] = {a.x * inv * wa.x, a.y * inv * wa.y, a.z * inv * wa.z, a.w * inv * wa.w,
                b.x * inv * wb.x, b.y * inv * wb.y, b.z * inv * wb.z, b.w * inv * wb.w};
  unsigned short* o = out + (size_t)row * 2048 + tid * 8;
  #pragma unroll
  for (int j = 0; j < 8; ++j) o[j] = f2bf(y[j]);
  if (out32) {
    float* o32 = out32 + (size_t)row * 2048 + tid * 8;
    *(float4*)&o32[0] = make_float4(y[0], y[1], y[2], y[3]);
    *(float4*)&o32[4] = make_float4(y[4], y[5], y[6], y[7]);
  }
}

__global__ __launch_bounds__(256) void f32_to_bf16_k(
    const float* __restrict__ in, unsigned short* __restrict__ out, int n)
{
  int i = (blockIdx.x * 256 + threadIdx.x) * 4;
  if (i + 3 < n) {
    float4 v = *(const float4*)&in[i];
    out[i + 0] = f2bf(v.x); out[i + 1] = f2bf(v.y);
    out[i + 2] = f2bf(v.z); out[i + 3] = f2bf(v.w);
  }
}

// ---------------------------------------------------------------------------
// Per-(b,s,h) head RMSNorm + RoPE, relayout to (B, NH, seq_total, 128) bf16.
// ---------------------------------------------------------------------------
__global__ __launch_bounds__(256) void qk_norm_rope(
    const float* __restrict__ raw, int ld, const float* __restrict__ nw,
    const float* __restrict__ cosT, const float* __restrict__ sinT,
    unsigned short* __restrict__ out,
    int S, int NH, int seq_total, int s_off, float premul)
{
  int rowid = blockIdx.x * 4 + (threadIdx.x >> 6);
  int lane  = threadIdx.x & 63;
  int b = rowid / (S * NH);
  int rem = rowid % (S * NH);
  int s = rem / NH, h = rem % NH;
  const float* src = raw + (size_t)(b * S + s) * ld + h * 128;
  float2 xv = *(const float2*)&src[lane * 2];
  float ss = xv.x * xv.x + xv.y * xv.y;
  #pragma unroll
  for (int off = 1; off < 64; off <<= 1) ss += __shfl_xor(ss, off);
  float inv = rsqrtf(ss * (1.f / 128.f) + 1e-6f);
  float yr = xv.x * inv * nw[lane * 2];
  float yi = xv.y * inv * nw[lane * 2 + 1];
  float c  = cosT[s * 64 + lane], sn = sinT[s * 64 + lane];
  float orr = (yr * c - yi * sn) * premul;
  float oi  = (yr * sn + yi * c) * premul;
  unsigned short* dst = out + ((size_t)(b * NH + h) * seq_total + (s + s_off)) * 128;
  dst[lane * 2]     = f2bf(orr);
  dst[lane * 2 + 1] = f2bf(oi);
}

__global__ __launch_bounds__(256) void v_relayout(
    const float* __restrict__ raw, int ld, unsigned short* __restrict__ out,
    int S, int NH, int seq_total, int s_off)
{
  int rowid = blockIdx.x * 4 + (threadIdx.x >> 6);
  int lane  = threadIdx.x & 63;
  int b = rowid / (S * NH);
  int rem = rowid % (S * NH);
  int s = rem / NH, h = rem % NH;
  const float* src = raw + (size_t)(b * S + s) * ld + h * 128;
  float2 xv = *(const float2*)&src[lane * 2];
  unsigned short* dst = out + ((size_t)(b * NH + h) * seq_total + (s + s_off)) * 128;
  dst[lane * 2]     = f2bf(xv.x);
  dst[lane * 2 + 1] = f2bf(xv.y);
}

// ---------------------------------------------------------------------------
// Flash attention (unchanged from r8): XOR-swizzled LDS + async dbuf reg
// staging, 64 q-rows/block, Sk tiles of 64.
// ---------------------------------------------------------------------------
__global__ __launch_bounds__(256) void attn_kernel(
    const unsigned short* __restrict__ q,
    const unsigned short* __restrict__ kbuf,
    const unsigned short* __restrict__ vbuf,
    unsigned short* __restrict__ o)
{
  const int SK = 1536;
  const int w = xcd_swz(blockIdx.x, gridDim.x);
  const int bh = w >> 4;
  const int b = bh >> 4, h = bh & 15, kvh = h >> 2;
  const int q0 = (w & 15) * 64;
  const int tid = threadIdx.x, lane = tid & 63, wid = tid >> 6;
  const int l16 = lane & 15, kb = (lane >> 4) * 8, r4 = (lane >> 4) * 4;
  __shared__ unsigned short KsL[64 * 128];
  __shared__ unsigned short VTL[128 * 64];
  __shared__ unsigned short PsL[4 * 16 * 64];
  const int sr0 = tid >> 4;
  const int scc = (tid & 15) * 8;

  const unsigned short* qrow =
      q + ((size_t)(b * 16 + h) * 1024 + q0 + wid * 16 + l16) * 128;
  bf16x8 qf[4];
  #pragma unroll
  for (int ks = 0; ks < 4; ++ks) qf[ks] = *(const bf16x8*)&qrow[ks * 32 + kb];
  float mrow[4] = {-1e30f, -1e30f, -1e30f, -1e30f};
  float lrow[4] = {0.f, 0.f, 0.f, 0.f};
  f32x4 oacc[8] = {};
  const unsigned short* kb_base = kbuf + (size_t)(b * 4 + kvh) * SK * 128;
  const unsigned short* vb_base = vbuf + (size_t)(b * 4 + kvh) * SK * 128;

  u16x8 k0[4], v0[4], k1[4], v1[4];

#define ATT_LOAD(kr, vr, kt1)                                                 \
  {                                                                           \
    _Pragma("unroll")                                                         \
    for (int i = 0; i < 4; ++i) {                                             \
      kr[i] = *(const u16x8*)&kb_base[(size_t)((kt1) + sr0 + 16 * i) * 128 + scc]; \
      vr[i] = *(const u16x8*)&vb_base[(size_t)((kt1) + sr0 + 16 * i) * 128 + scc]; \
    }                                                                         \
  }

#define ATT_STAGE(kr, vr)                                                     \
  {                                                                           \
    _Pragma("unroll")                                                         \
    for (int i = 0; i < 4; ++i) {                                             \
      int rr = sr0 + 16 * i;                                                  \
      *(u16x8*)&KsL[rr * 128 + (((scc >> 3) ^ (rr & 7)) << 3)] = kr[i];       \
      _Pragma("unroll")                                                       \
      for (int j = 0; j < 8; ++j)                                             \
        VTL[(scc + j) * 64 + ((((rr >> 3) ^ ((scc + j) >> 3)) & 7) << 3) + (rr & 7)] = vr[i][j]; \
    }                                                                         \
  }

  auto compute = [&]() {
    f32x4 sacc[4] = {};
    #pragma unroll
    for (int ks = 0; ks < 4; ++ks) {
      #pragma unroll
      for (int ni = 0; ni < 4; ++ni) {
        int rr = ni * 16 + l16;
        bf16x8 kf = *(const bf16x8*)
            &KsL[rr * 128 + ((((ks * 32 + kb) >> 3) ^ (rr & 7)) << 3)];
        sacc[ni] = __builtin_amdgcn_mfma_f32_16x16x32_bf16(qf[ks], kf, sacc[ni], 0, 0, 0);
      }
    }
    float pv[4][4], alpha[4];
    #pragma unroll
    for (int r = 0; r < 4; ++r) {
      float tm = fmaxf(fmaxf(sacc[0][r], sacc[1][r]), fmaxf(sacc[2][r], sacc[3][r]));
      #pragma unroll
      for (int off = 1; off < 16; off <<= 1) tm = fmaxf(tm, __shfl_xor(tm, off));
      float mn = fmaxf(mrow[r], tm);
      alpha[r] = __expf(mrow[r] - mn);
      float s = 0.f;
      #pragma unroll
      for (int ni = 0; ni < 4; ++ni) {
        float p = __expf(sacc[ni][r] - mn);
        pv[ni][r] = p; s += p;
      }
      #pragma unroll
      for (int off = 1; off < 16; off <<= 1) s += __shfl_xor(s, off);
      lrow[r] = lrow[r] * alpha[r] + s;
      mrow[r] = mn;
    }
    #pragma unroll
    for (int ni = 0; ni < 8; ++ni)
      #pragma unroll
      for (int r = 0; r < 4; ++r) oacc[ni][r] *= alpha[r];
    #pragma unroll
    for (int ni = 0; ni < 4; ++ni)
      #pragma unroll
      for (int r = 0; r < 4; ++r) {
        int row = r4 + r, col = ni * 16 + l16;
        PsL[wid * 1024 + row * 64 + ((((col >> 3) ^ (row & 7)) & 7) << 3) + (col & 7)]
            = f2bf(pv[ni][r]);
      }
    asm volatile("s_waitcnt lgkmcnt(0)" ::: "memory");
    __builtin_amdgcn_sched_barrier(0);
    #pragma unroll
    for (int ks = 0; ks < 2; ++ks) {
      bf16x8 pf = *(const bf16x8*)
          &PsL[wid * 1024 + l16 * 64 + ((((ks * 32 + kb) >> 3) ^ (l16 & 7)) << 3)];
      #pragma unroll
      for (int ni = 0; ni < 8; ++ni) {
        int d = ni * 16 + l16;
        bf16x8 vf = *(const bf16x8*)
            &VTL[d * 64 + ((((ks * 32 + kb) >> 3) ^ ((d >> 3) & 7)) << 3)];
        oacc[ni] = __builtin_amdgcn_mfma_f32_16x16x32_bf16(pf, vf, oacc[ni], 0, 0, 0);
      }
    }
  };

  ATT_LOAD(k0, v0, 0);
  for (int t = 0; t < 24; t += 2) {
    ATT_STAGE(k0, v0);
    ATT_LOAD(k1, v1, (t + 1) * 64);
    asm volatile("s_waitcnt lgkmcnt(0)" ::: "memory");
    __builtin_amdgcn_s_barrier();
    __builtin_amdgcn_sched_barrier(0);
    compute();
    __builtin_amdgcn_sched_barrier(0);
    __builtin_amdgcn_s_barrier();
    ATT_STAGE(k1, v1);
    if (t + 2 < 24) ATT_LOAD(k0, v0, (t + 2) * 64);
    asm volatile("s_waitcnt lgkmcnt(0)" ::: "memory");
    __builtin_amdgcn_s_barrier();
    __builtin_amdgcn_sched_barrier(0);
    compute();
    __builtin_amdgcn_sched_barrier(0);
    __builtin_amdgcn_s_barrier();
  }
#undef ATT_LOAD
#undef ATT_STAGE

  #pragma unroll
  for (int ni = 0; ni < 8; ++ni)
    #pragma unroll
    for (int r = 0; r < 4; ++r) {
      float val = oacc[ni][r] / lrow[r];
      size_t row = (size_t)b * 1024 + q0 + wid * 16 + r4 + r;
      o[row * 2048 + h * 128 + ni * 16 + l16] = f2bf(val);
    }
}

// ---------------------------------------------------------------------------
// Router: one wave per token, f32 input (exact), f32 accumulate.
// ---------------------------------------------------------------------------
__global__ __launch_bounds__(64) void router_kernel(
    const float* __restrict__ xt32, const float* __restrict__ rw,
    int* __restrict__ topi, float* __restrict__ topw, int* __restrict__ counts)
{
  int t = blockIdx.x, lane = threadIdx.x;
  float acc[8] = {};
  const float* x = xt32 + (size_t)t * 2048;
  for (int d0 = lane * 4; d0 < 2048; d0 += 256) {
    float4 xv = *(const float4*)&x[d0];
    float xa[4] = {xv.x, xv.y, xv.z, xv.w};
    #pragma unroll
    for (int j = 0; j < 4; ++j) {
      const float4 r0 = *(const float4*)&rw[(d0 + j) * 8];
      const float4 r1 = *(const float4*)&rw[(d0 + j) * 8 + 4];
      acc[0] += xa[j] * r0.x; acc[1] += xa[j] * r0.y;
      acc[2] += xa[j] * r0.z; acc[3] += xa[j] * r0.w;
      acc[4] += xa[j] * r1.x; acc[5] += xa[j] * r1.y;
      acc[6] += xa[j] * r1.z; acc[7] += xa[j] * r1.w;
    }
  }
  #pragma unroll
  for (int e = 0; e < 8; ++e)
    #pragma unroll
    for (int off = 1; off < 64; off <<= 1) acc[e] += __shfl_xor(acc[e], off);
  if (lane == 0) {
    float v0 = acc[0]; int e0 = 0;
    #pragma unroll
    for (int e = 1; e < 8; ++e) if (acc[e] > v0) { v0 = acc[e]; e0 = e; }
    float v1 = -1e30f; int e1 = 0;
    #pragma unroll
    for (int e = 0; e < 8; ++e) if (e != e0 && acc[e] > v1) { v1 = acc[e]; e1 = e; }
    float x1 = expf(v1 - v0);
    float w0 = 1.f / (1.f + x1);
    float w1 = x1 / (1.f + x1);
    topi[2 * t] = e0; topi[2 * t + 1] = e1;
    topw[2 * t] = w0; topw[2 * t + 1] = w1;
    atomicAdd(&counts[e0], 1);
    atomicAdd(&counts[e1], 1);
  }
}

__global__ void scan_offsets(const int* __restrict__ counts, int* __restrict__ offsets)
{
  if (threadIdx.x == 0 && blockIdx.x == 0) {
    int a = 0;
    for (int e = 0; e < 8; ++e) { offsets[e] = a; a += counts[e]; }
    offsets[8] = a;
  }
}

__global__ __launch_bounds__(256) void scatter_pairs(
    const int* __restrict__ topi, const int* __restrict__ offsets,
    int* __restrict__ fill, int* __restrict__ pair_token, int* __restrict__ token_slot)
{
  int t = blockIdx.x * 256 + threadIdx.x;
  if (t >= 2048) return;
  #pragma unroll
  for (int k = 0; k < 2; ++k) {
    int e = topi[2 * t + k];
    int slot = offsets[e] + atomicAdd(&fill[e], 1);
    pair_token[slot] = t;
    token_slot[2 * t + k] = slot;
  }
}

// act_silu over summed split-K partials: g/u = gu0 + gu1.
__global__ __launch_bounds__(256) void act_silu2(
    const float* __restrict__ gu0, const float* __restrict__ gu1,
    unsigned short* __restrict__ act)
{
  int p = blockIdx.x;
  int c = threadIdx.x * 4;
  float4 g0 = *(const float4*)&gu0[(size_t)p * 2048 + c];
  float4 g1 = *(const float4*)&gu1[(size_t)p * 2048 + c];
  float4 u0 = *(const float4*)&gu0[(size_t)p * 2048 + 1024 + c];
  float4 u1 = *(const float4*)&gu1[(size_t)p * 2048 + 1024 + c];
  float gg[4] = {g0.x + g1.x, g0.y + g1.y, g0.z + g1.z, g0.w + g1.w};
  float uu[4] = {u0.x + u1.x, u0.y + u1.y, u0.z + u1.z, u0.w + u1.w};
  #pragma unroll
  for (int j = 0; j < 4; ++j) {
    float a = gg[j] / (1.f + __expf(-gg[j])) * uu[j];
    act[(size_t)p * 1024 + c + j] = f2bf(a);
  }
}

// combine over summed split-K partials: eo = eo0 + eo1.
__global__ __launch_bounds__(256) void moe_combine2(
    float* __restrict__ out, const float* __restrict__ eo0,
    const float* __restrict__ eo1,
    const int* __restrict__ token_slot, const float* __restrict__ topw)
{
  int t = blockIdx.x;
  int c = threadIdx.x * 8;
  int s0 = token_slot[2 * t], s1 = token_slot[2 * t + 1];
  float w0 = topw[2 * t], w1 = topw[2 * t + 1];
  #pragma unroll
  for (int j0 = 0; j0 < 8; j0 += 4) {
    float4 a0 = *(const float4*)&eo0[(size_t)s0 * 2048 + c + j0];
    float4 a1 = *(const float4*)&eo1[(size_t)s0 * 2048 + c + j0];
    float4 b0 = *(const float4*)&eo0[(size_t)s1 * 2048 + c + j0];
    float4 b1 = *(const float4*)&eo1[(size_t)s1 * 2048 + c + j0];
    float4 v = *(const float4*)&out[(size_t)t * 2048 + c + j0];
    v.x += w0 * (a0.x + a1.x) + w1 * (b0.x + b1.x);
    v.y += w0 * (a0.y + a1.y) + w1 * (b0.y + b1.y);
    v.z += w0 * (a0.z + a1.z) + w1 * (b0.z + b1.z);
    v.w += w0 * (a0.w + a1.w) + w1 * (b0.w + b1.w);
    *(float4*)&out[(size_t)t * 2048 + c + j0] = v;
  }
}

// ---------------------------------------------------------------------------
extern "C" void kernel_launch(void* const* d_in, const int* in_sizes, int n_in,
                              void* d_out, int out_size, void* d_ws, size_t ws_size,
                              hipStream_t stream)
{
  const float* hidden  = (const float*)d_in[0];
  const float* enc     = (const float*)d_in[1];
  const float* img_cos = (const float*)d_in[2];
  const float* img_sin = (const float*)d_in[3];
  const float* txt_cos = (const float*)d_in[4];
  const float* txt_sin = (const float*)d_in[5];
  const float* norm1_w = (const float*)d_in[6];
  const float* norm2_w = (const float*)d_in[7];
  const float* wq      = (const float*)d_in[8];
  const float* wk      = (const float*)d_in[9];
  const float* wv      = (const float*)d_in[10];
  const float* wk_txt  = (const float*)d_in[11];
  const float* wv_txt  = (const float*)d_in[12];
  const float* wo      = (const float*)d_in[13];
  const float* q_norm_w       = (const float*)d_in[14];
  const float* k_norm_w       = (const float*)d_in[15];
  const float* added_k_norm_w = (const float*)d_in[16];
  const float* router_w       = (const float*)d_in[17];
  const float* gate_up_proj   = (const float*)d_in[18];
  const float* down_proj      = (const float*)d_in[19];
  float* out = (float*)d_out;

  char* ws = (char*)d_ws;
  size_t off = 0;
  auto alloc = [&](size_t bytes) {
    void* p = ws + off;
    off += (bytes + 255) & ~(size_t)255;
    return p;
  };
  // --- bf16 transposed weights ---
  unsigned short* wqkvT  = (unsigned short*)alloc(3072ULL * 2048 * 2); // q|k|v rows
  unsigned short* wkvtT  = (unsigned short*)alloc(1024ULL * 2048 * 2); // k_txt|v_txt
  unsigned short* woT    = (unsigned short*)alloc(2048ULL * 2048 * 2);
  unsigned short* gupT   = (unsigned short*)alloc(8ULL * 2048 * 2048 * 2);
  unsigned short* dnT    = (unsigned short*)alloc(8ULL * 2048 * 1024 * 2);
  // --- activations ---
  unsigned short* x_bf   = (unsigned short*)alloc(2048ULL * 2048 * 2);
  unsigned short* enc_bf = (unsigned short*)alloc(1024ULL * 2048 * 2);
  float* qkvC = (float*)alloc(4096ULL * 2048 * 4); // [2048][3072] early; partial-0 late
  float* gu0  = qkvC;                              // alias (disjoint lifetimes)
  float* gu1  = (float*)alloc(4096ULL * 2048 * 4); // partial-1
  float* kvtC = (float*)alloc(1024ULL * 1024 * 4); // [1024][1024] k_txt|v_txt
  unsigned short* qb   = (unsigned short*)alloc(2048ULL * 2048 * 2);
  unsigned short* kbuf = (unsigned short*)alloc(2ULL * 4 * 1536 * 128 * 2);
  unsigned short* vbuf = (unsigned short*)alloc(2ULL * 4 * 1536 * 128 * 2);
  unsigned short* obuf = (unsigned short*)alloc(2048ULL * 2048 * 2);
  unsigned short* act  = obuf;                     // alias (obuf dead after wo GEMM)
  unsigned short* xt   = (unsigned short*)alloc(2048ULL * 2048 * 2);
  float* xt32 = (float*)alloc(2048ULL * 2048 * 4);
  int*   ctrl  = (int*)alloc(64 * sizeof(int));    // counts[8] fill[8] offsets[9]
  int*   topi  = (int*)alloc(4096 * 4);
  float* topw  = (float*)alloc(4096 * 4);
  int*   tslot = (int*)alloc(4096 * 4);
  int*   ptok  = (int*)alloc(4096 * 4);
  unsigned short* zbuf = (unsigned short*)alloc(256);
  int* counts = ctrl, * fill = ctrl + 8, * offsets = ctrl + 16;

  hipMemsetAsync(ctrl, 0, 64, stream);
  hipMemsetAsync(zbuf, 0, 256, stream);

  const float scale = 0.08838834764831845f;  // 1/sqrt(128)

  // --- weight preprocessing: f32 [K][N] -> bf16 [N][K] ---
  convert_w<<<dim3(32, 32, 1), 256, 0, stream>>>(wq,     wqkvT,                    2048, 2048);
  convert_w<<<dim3(32,  8, 1), 256, 0, stream>>>(wk,     wqkvT + 2048ULL * 2048,   2048, 512);
  convert_w<<<dim3(32,  8, 1), 256, 0, stream>>>(wv,     wqkvT + 2560ULL * 2048,   2048, 512);
  convert_w<<<dim3(32,  8, 1), 256, 0, stream>>>(wk_txt, wkvtT,                    2048, 512);
  convert_w<<<dim3(32,  8, 1), 256, 0, stream>>>(wv_txt, wkvtT + 512ULL * 2048,    2048, 512);
  convert_w<<<dim3(32, 32, 1), 256, 0, stream>>>(wo,     woT,                      2048, 2048);
  convert_w<<<dim3(32, 32, 8), 256, 0, stream>>>(gate_up_proj, gupT,               2048, 2048);
  convert_w<<<dim3(16, 32, 8), 256, 0, stream>>>(down_proj,    dnT,                1024, 2048);

  rmsnorm_rows<<<2048, 256, 0, stream>>>(hidden, norm1_w, x_bf, nullptr);
  f32_to_bf16_k<<<2048, 256, 0, stream>>>(enc, enc_bf, 1024 * 2048);

  // fused qkv projection: [2048][2048] @ [3072][2048]^T -> [2048][3072]
  gemm_bb<<<384, 256, 0, stream>>>(x_bf, wqkvT, qkvC, nullptr, 2048, 3072, 2048);
  // fused k/v txt projection: [1024][2048] @ [1024][2048]^T -> [1024][1024]
  gemm_bb<<<64, 256, 0, stream>>>(enc_bf, wkvtT, kvtC, nullptr, 1024, 1024, 2048);

  qk_norm_rope<<<8192, 256, 0, stream>>>(qkvC, 3072, q_norm_w, img_cos, img_sin, qb,
                                         1024, 16, 1024, 0, scale);
  qk_norm_rope<<<2048, 256, 0, stream>>>(qkvC + 2048, 3072, k_norm_w, img_cos, img_sin, kbuf,
                                         1024, 4, 1536, 0, 1.0f);
  qk_norm_rope<<<1024, 256, 0, stream>>>(kvtC, 1024, added_k_norm_w, txt_cos, txt_sin, kbuf,
                                         512, 4, 1536, 1024, 1.0f);
  v_relayout<<<2048, 256, 0, stream>>>(qkvC + 2560, 3072, vbuf, 1024, 4, 1536, 0);
  v_relayout<<<1024, 256, 0, stream>>>(kvtC + 512, 1024, vbuf, 512, 4, 1536, 1024);

  attn_kernel<<<512, 256, 0, stream>>>(qb, kbuf, vbuf, obuf);

  gemm_bb<<<256, 256, 0, stream>>>(obuf, woT, out, hidden, 2048, 2048, 2048);

  rmsnorm_rows<<<2048, 256, 0, stream>>>(out, norm2_w, xt, xt32);
  router_kernel<<<2048, 64, 0, stream>>>(xt32, router_w, topi, topw, counts);
  scan_offsets<<<1, 64, 0, stream>>>(counts, offsets);
  scatter_pairs<<<8, 256, 0, stream>>>(topi, offsets, fill, ptok, tslot);

  // gate_up: split-K=2 into gu0/gu1
  gemm_moe_256sk<<<512, 512, 0, stream>>>(xt, gupT, gu0, gu1,
                                          counts, offsets, ptok, zbuf, 1, 2048, 2048);
  act_silu2<<<4096, 256, 0, stream>>>(gu0, gu1, act);
  // down: split-K=2 into gu0/gu1 (reused as eo partials)
  gemm_moe_256sk<<<512, 512, 0, stream>>>(act, dnT, gu0, gu1,
                                          counts, offsets, ptok, zbuf, 0, 1024, 2048);
  moe_combine2<<<2048, 256, 0, stream>>>(out, gu0, gu1, tslot, topw);
}

// Round 12
// 562.916 us; speedup vs baseline: 1.1605x; 1.1194x over previous
//
#include <hip/hip_runtime.h>

// ---------------------------------------------------------------------------
// NucleusMoEImageTransformerBlock round 12.
// B=2 SI=1024 ST=512 D=2048 H=16 KV=4 HD=128 E=8 F=1024 TOPK=2
// Round-12: (1) attention QBLK=128 / 8 waves / grid 256 + setprio around
// MFMA (stage cost per q-row halves); (2) launch fusion: convert_all (8->1),
// prep_all (5->1), rmsnorm_router (2->1, xt32 eliminated); (3) MoE split-K
// grid 1024 with 8 bm slots (handles counts up to 2048). 27 -> 15 dispatches.
// ---------------------------------------------------------------------------

typedef __attribute__((ext_vector_type(8))) __bf16 bf16x8;
typedef __attribute__((ext_vector_type(8))) unsigned short u16x8;
typedef __attribute__((ext_vector_type(4))) float f32x4;

__device__ __forceinline__ unsigned short f2bf(float x) {
  unsigned u = __builtin_bit_cast(unsigned, x);
  u += 0x7fffu + ((u >> 16) & 1u);        // RNE
  return (unsigned short)(u >> 16);
}
__device__ __forceinline__ float bf2f(unsigned short b) {
  return __builtin_bit_cast(float, ((unsigned)b) << 16);
}

__device__ __forceinline__ void glds16(const unsigned short* g, unsigned short* l) {
  __builtin_amdgcn_global_load_lds(
      (const __attribute__((address_space(1))) void*)g,
      (__attribute__((address_space(3))) void*)l, 16, 0, 0);
}

// m204 bijective XCD chunk swizzle.
__device__ __forceinline__ int xcd_swz(int orig, int nwg) {
  int q = nwg >> 3, r = nwg & 7;
  int xcd = orig & 7, idx = orig >> 3;
  int base = (xcd < r) ? xcd * (q + 1) : r * (q + 1) + (xcd - r) * q;
  return base + idx;
}

// ---------------------------------------------------------------------------
// Batched weight convert+transpose: 8 jobs, W f32 [K][N] -> WT bf16 [N][K].
// ---------------------------------------------------------------------------
struct CvtJobs {
  const float* src[8];
  unsigned short* dst[8];
  int K[8];
  int N[8];
  int off[9];
};

__global__ __launch_bounds__(256) void convert_all(CvtJobs jb)
{
  __shared__ unsigned short T[64][66];
  const int bid = blockIdx.x;
  int j = 0;
  #pragma unroll
  for (int i = 0; i < 8; ++i) if (bid >= jb.off[i + 1]) j = i + 1;
  const int local = bid - jb.off[j];
  const int K = jb.K[j], N = jb.N[j];
  const int kb = K >> 6, nb = N >> 6;
  const int kt = local % kb;
  const int rest = local / kb;
  const int nt = rest % nb, zi = rest / nb;
  const float* Wz = jb.src[j] + (size_t)zi * K * N;
  unsigned short* WTz = jb.dst[j] + (size_t)zi * K * N;
  const int k0 = kt * 64, n0 = nt * 64;
  const int tid = threadIdx.x;
  #pragma unroll
  for (int i = tid; i < 64 * 16; i += 256) {
    int k = i >> 4, n4 = (i & 15) * 4;
    float4 v = *(const float4*)&Wz[(size_t)(k0 + k) * N + n0 + n4];
    T[n4 + 0][k] = f2bf(v.x);
    T[n4 + 1][k] = f2bf(v.y);
    T[n4 + 2][k] = f2bf(v.z);
    T[n4 + 3][k] = f2bf(v.w);
  }
  __syncthreads();
  #pragma unroll
  for (int i = tid; i < 64 * 8; i += 256) {
    int n = i >> 3, k8 = (i & 7) * 8;
    *(u16x8*)&WTz[(size_t)(n0 + n) * K + k0 + k8] = *(const u16x8*)&T[n][k8];
  }
}

// ---------------------------------------------------------------------------
// Dense GEMM: C[M,N] = A[M,K] @ BT[N,K]^T (+resid). bf16 in, f32 out.
// 128x128 tile, counted-vmcnt dbuf pipeline (unchanged).
// ---------------------------------------------------------------------------
__global__ __launch_bounds__(256) void gemm_bb(
    const unsigned short* __restrict__ A, const unsigned short* __restrict__ BT,
    float* __restrict__ C, const float* __restrict__ resid,
    int M, int N, int K)
{
  __shared__ unsigned short As[2][128 * 64];
  __shared__ unsigned short Bs[2][128 * 64];
  const int mb = M >> 7;
  const int w = xcd_swz(blockIdx.x, gridDim.x);
  const int bm = (w % mb) * 128, bn = (w / mb) * 128;
  const int tid = threadIdx.x, lane = tid & 63, wid = tid >> 6;
  const int wm = (wid >> 1) * 64, wn = (wid & 1) * 64;
  const int l16 = lane & 15, g4 = lane >> 4;
  const int rseg = lane >> 3;
  const int csw  = ((lane & 7) ^ rseg) * 8;
  const unsigned short* aSrc[4];
  const unsigned short* bSrc[4];
  #pragma unroll
  for (int p = 0; p < 4; ++p) {
    int row = (p * 4 + wid) * 8 + rseg;
    aSrc[p] = A  + (size_t)(bm + row) * K + csw;
    bSrc[p] = BT + (size_t)(bn + row) * K + csw;
  }
  f32x4 acc[4][4] = {};
  const int NT = K >> 6;
  #pragma unroll
  for (int p = 0; p < 4; ++p) glds16(aSrc[p], &As[0][(p * 4 + wid) * 512]);
  #pragma unroll
  for (int p = 0; p < 4; ++p) glds16(bSrc[p], &Bs[0][(p * 4 + wid) * 512]);
  for (int t = 0; t < NT; ++t) {
    const int cur = t & 1;
    if (t + 1 < NT) {
      const int k0 = (t + 1) << 6;
      #pragma unroll
      for (int p = 0; p < 4; ++p) glds16(aSrc[p] + k0, &As[cur ^ 1][(p * 4 + wid) * 512]);
      #pragma unroll
      for (int p = 0; p < 4; ++p) glds16(bSrc[p] + k0, &Bs[cur ^ 1][(p * 4 + wid) * 512]);
      asm volatile("s_waitcnt vmcnt(8)" ::: "memory");
    } else {
      asm volatile("s_waitcnt vmcnt(0)" ::: "memory");
    }
    __builtin_amdgcn_s_barrier();
    __builtin_amdgcn_sched_barrier(0);
    const unsigned short* ab = &As[cur][0];
    const unsigned short* bb = &Bs[cur][0];
    #pragma unroll
    for (int ks = 0; ks < 2; ++ks) {
      bf16x8 af[4], bf[4];
      #pragma unroll
      for (int i = 0; i < 4; ++i) {
        int ra = wm + i * 16 + l16;
        int rb = wn + i * 16 + l16;
        int ch = ((ks * 4 + g4) ^ (l16 & 7)) * 8;
        af[i] = *(const bf16x8*)&ab[ra * 64 + ch];
        bf[i] = *(const bf16x8*)&bb[rb * 64 + ch];
      }
      #pragma unroll
      for (int mi = 0; mi < 4; ++mi)
        #pragma unroll
        for (int ni = 0; ni < 4; ++ni)
          acc[mi][ni] = __builtin_amdgcn_mfma_f32_16x16x32_bf16(af[mi], bf[ni], acc[mi][ni], 0, 0, 0);
    }
    __builtin_amdgcn_sched_barrier(0);
    __builtin_amdgcn_s_barrier();
  }
  const int r4 = g4 * 4;
  #pragma unroll
  for (int mi = 0; mi < 4; ++mi)
    #pragma unroll
    for (int ni = 0; ni < 4; ++ni)
      #pragma unroll
      for (int r = 0; r < 4; ++r) {
        int row = bm + wm + mi * 16 + r4 + r;
        int col = bn + wn + ni * 16 + l16;
        float v = acc[mi][ni][r];
        if (resid) v += resid[(size_t)row * N + col];
        C[(size_t)row * N + col] = v;
      }
}

// ---------------------------------------------------------------------------
// Expert-batched MoE GEMM, 256x256 tile, split-K=2. Grid 1024 = 8bm x 2kh x
// 8bn x 8e, XCD-swizzled -> one expert per XCD; working blocks are a
// contiguous 32-prefix of each XCD's 128-chunk.
// ---------------------------------------------------------------------------
__global__ __launch_bounds__(512, 1) void gemm_moe_256sk(
    const unsigned short* __restrict__ A, const unsigned short* __restrict__ BTall,
    float* __restrict__ C0, float* __restrict__ C1,
    const int* __restrict__ counts, const int* __restrict__ offsets,
    const int* __restrict__ pair_token, const unsigned short* __restrict__ zbuf,
    int gather, int K, int N)
{
  const int w = xcd_swz(blockIdx.x, gridDim.x);
  const int e = w >> 7;
  const int local = w & 127;
  const int bm = ((local >> 4) & 7) * 256;
  const int kh = (local >> 3) & 1;
  const int bn = (local & 7) * 256;
  const int cnt = counts[e];
  if (bm >= cnt) return;
  const int base = offsets[e];
  const int Kh = K >> 1;
  float* __restrict__ C = kh ? C1 : C0;
  __shared__ unsigned short As[256 * 64];
  __shared__ unsigned short Bs[256 * 64];
  __shared__ int rowmap[256];
  const int tid = threadIdx.x, lane = tid & 63, wid = tid >> 6;
  const int wr = wid >> 2, wc = wid & 3;
  const int l16 = lane & 15, g4 = lane >> 4;
  const int rseg = lane >> 3;
  const int csw  = ((lane & 7) ^ rseg) * 8;
  if (tid < 256) {
    int lr = bm + tid;
    rowmap[tid] = (lr < cnt) ? (gather ? pair_token[base + lr] : base + lr) : -1;
  }
  __syncthreads();
  const unsigned short* BT = BTall + (size_t)e * N * K;
  const unsigned short* aSrc[4];
  const unsigned short* bSrc[4];
  int aOk[4];
  #pragma unroll
  for (int p = 0; p < 4; ++p) {
    int row = (p * 8 + wid) * 8 + rseg;
    int tok = rowmap[row];
    aOk[p] = (tok >= 0);
    aSrc[p] = aOk[p] ? (A + (size_t)tok * K + kh * Kh + csw) : (zbuf + csw);
    bSrc[p] = BT + (size_t)(bn + row) * K + kh * Kh + csw;
  }
  f32x4 acc[8][4] = {};
  const int NT = Kh >> 6;
  for (int t = 0; t < NT; ++t) {
    const int k0 = t << 6;
    #pragma unroll
    for (int p = 0; p < 4; ++p)
      glds16(aSrc[p] + (aOk[p] ? k0 : 0), &As[(p * 8 + wid) * 512]);
    #pragma unroll
    for (int p = 0; p < 4; ++p)
      glds16(bSrc[p] + k0, &Bs[(p * 8 + wid) * 512]);
    __syncthreads();
    #pragma unroll
    for (int ks = 0; ks < 2; ++ks) {
      const int ch = ((ks * 4 + g4) ^ (l16 & 7)) * 8;
      bf16x8 bf[4];
      #pragma unroll
      for (int j = 0; j < 4; ++j)
        bf[j] = *(const bf16x8*)&Bs[(wc * 64 + j * 16 + l16) * 64 + ch];
      #pragma unroll
      for (int mi = 0; mi < 8; ++mi) {
        bf16x8 af = *(const bf16x8*)&As[(wr * 128 + mi * 16 + l16) * 64 + ch];
        #pragma unroll
        for (int ni = 0; ni < 4; ++ni)
          acc[mi][ni] = __builtin_amdgcn_mfma_f32_16x16x32_bf16(af, bf[ni], acc[mi][ni], 0, 0, 0);
      }
    }
    __syncthreads();
  }
  const int r4 = g4 * 4;
  #pragma unroll
  for (int mi = 0; mi < 8; ++mi)
    #pragma unroll
    for (int ni = 0; ni < 4; ++ni)
      #pragma unroll
      for (int r = 0; r < 4; ++r) {
        int lrow = bm + wr * 128 + mi * 16 + r4 + r;
        int col  = bn + wc * 64 + ni * 16 + l16;
        if (lrow < cnt)
          C[(size_t)(base + lrow) * N + col] = acc[mi][ni][r];
      }
}

// ---------------------------------------------------------------------------
// RMSNorm over D=2048, f32 in -> bf16 out. (norm1)
// ---------------------------------------------------------------------------
__global__ __launch_bounds__(256) void rmsnorm_rows(
    const float* __restrict__ in, const float* __restrict__ w,
    unsigned short* __restrict__ out)
{
  const int row = blockIdx.x;
  const int tid = threadIdx.x;
  const float* x = in + (size_t)row * 2048;
  float4 a = *(const float4*)&x[tid * 8];
  float4 b = *(const float4*)&x[tid * 8 + 4];
  float s = a.x*a.x + a.y*a.y + a.z*a.z + a.w*a.w
          + b.x*b.x + b.y*b.y + b.z*b.z + b.w*b.w;
  #pragma unroll
  for (int off = 1; off < 64; off <<= 1) s += __shfl_xor(s, off);
  __shared__ float red[4];
  if ((tid & 63) == 0) red[tid >> 6] = s;
  __syncthreads();
  float inv = rsqrtf((red[0] + red[1] + red[2] + red[3]) * (1.f / 2048.f) + 1e-6f);
  float4 wa = *(const float4*)&w[tid * 8];
  float4 wb = *(const float4*)&w[tid * 8 + 4];
  unsigned short* o = out + (size_t)row * 2048 + tid * 8;
  o[0] = f2bf(a.x * inv * wa.x); o[1] = f2bf(a.y * inv * wa.y);
  o[2] = f2bf(a.z * inv * wa.z); o[3] = f2bf(a.w * inv * wa.w);
  o[4] = f2bf(b.x * inv * wb.x); o[5] = f2bf(b.y * inv * wb.y);
  o[6] = f2bf(b.z * inv * wb.z); o[7] = f2bf(b.w * inv * wb.w);
}

// ---------------------------------------------------------------------------
// Fused RMSNorm(norm2) + router: bf16 xt out + exact-f32 top-2 routing.
// ---------------------------------------------------------------------------
__global__ __launch_bounds__(256) void rmsnorm_router(
    const float* __restrict__ in, const float* __restrict__ w,
    unsigned short* __restrict__ xt, const float* __restrict__ rw,
    int* __restrict__ topi, float* __restrict__ topw, int* __restrict__ counts)
{
  const int row = blockIdx.x;
  const int tid = threadIdx.x, lane = tid & 63, wid = tid >> 6;
  const float* x = in + (size_t)row * 2048;
  float4 a = *(const float4*)&x[tid * 8];
  float4 b = *(const float4*)&x[tid * 8 + 4];
  float s = a.x*a.x + a.y*a.y + a.z*a.z + a.w*a.w
          + b.x*b.x + b.y*b.y + b.z*b.z + b.w*b.w;
  #pragma unroll
  for (int off = 1; off < 64; off <<= 1) s += __shfl_xor(s, off);
  __shared__ float red[4];
  __shared__ float rl[4][8];
  if (lane == 0) red[wid] = s;
  __syncthreads();
  float inv = rsqrtf((red[0] + red[1] + red[2] + red[3]) * (1.f / 2048.f) + 1e-6f);
  float4 wa = *(const float4*)&w[tid * 8];
  float4 wb = *(const float4*)&w[tid * 8 + 4];
  float y[8] = {a.x * inv * wa.x, a.y * inv * wa.y, a.z * inv * wa.z, a.w * inv * wa.w,
                b.x * inv * wb.x, b.y * inv * wb.y, b.z * inv * wb.z, b.w * inv * wb.w};
  unsigned short* o = xt + (size_t)row * 2048 + tid * 8;
  #pragma unroll
  for (int j = 0; j < 8; ++j) o[j] = f2bf(y[j]);
  // router logits from exact f32 y
  float lg[8] = {};
  #pragma unroll
  for (int j = 0; j < 8; ++j) {
    int d = tid * 8 + j;
    const float4 r0 = *(const float4*)&rw[d * 8];
    const float4 r1 = *(const float4*)&rw[d * 8 + 4];
    lg[0] += y[j] * r0.x; lg[1] += y[j] * r0.y; lg[2] += y[j] * r0.z; lg[3] += y[j] * r0.w;
    lg[4] += y[j] * r1.x; lg[5] += y[j] * r1.y; lg[6] += y[j] * r1.z; lg[7] += y[j] * r1.w;
  }
  #pragma unroll
  for (int e = 0; e < 8; ++e)
    #pragma unroll
    for (int off = 1; off < 64; off <<= 1) lg[e] += __shfl_xor(lg[e], off);
  if (lane == 0) {
    #pragma unroll
    for (int e = 0; e < 8; ++e) rl[wid][e] = lg[e];
  }
  __syncthreads();
  if (tid == 0) {
    float l[8];
    #pragma unroll
    for (int e = 0; e < 8; ++e) l[e] = rl[0][e] + rl[1][e] + rl[2][e] + rl[3][e];
    float v0 = l[0]; int e0 = 0;
    #pragma unroll
    for (int e = 1; e < 8; ++e) if (l[e] > v0) { v0 = l[e]; e0 = e; }
    float v1 = -1e30f; int e1 = 0;
    #pragma unroll
    for (int e = 0; e < 8; ++e) if (e != e0 && l[e] > v1) { v1 = l[e]; e1 = e; }
    float x1 = expf(v1 - v0);
    float w0 = 1.f / (1.f + x1);
    float w1 = x1 / (1.f + x1);
    topi[2 * row] = e0; topi[2 * row + 1] = e1;
    topw[2 * row] = w0; topw[2 * row + 1] = w1;
    atomicAdd(&counts[e0], 1);
    atomicAdd(&counts[e1], 1);
  }
}

__global__ __launch_bounds__(256) void f32_to_bf16_k(
    const float* __restrict__ in, unsigned short* __restrict__ out, int n)
{
  int i = (blockIdx.x * 256 + threadIdx.x) * 4;
  if (i + 3 < n) {
    float4 v = *(const float4*)&in[i];
    out[i + 0] = f2bf(v.x); out[i + 1] = f2bf(v.y);
    out[i + 2] = f2bf(v.z); out[i + 3] = f2bf(v.w);
  }
}

// ---------------------------------------------------------------------------
// Fused q/k/v head-norm + RoPE + relayout (5 old launches -> 1).
// Jobs by block range: 0:q(8192) 1:k_img(2048) 2:k_txt(1024) 3:v_img(2048)
// 4:v_txt(1024). Total grid 14336.
// ---------------------------------------------------------------------------
__global__ __launch_bounds__(256) void prep_all(
    const float* __restrict__ qkvC, const float* __restrict__ kvtC,
    const float* __restrict__ q_norm_w, const float* __restrict__ k_norm_w,
    const float* __restrict__ added_k_norm_w,
    const float* __restrict__ img_cos, const float* __restrict__ img_sin,
    const float* __restrict__ txt_cos, const float* __restrict__ txt_sin,
    unsigned short* __restrict__ qb, unsigned short* __restrict__ kbuf,
    unsigned short* __restrict__ vbuf, float scale)
{
  const int bid = blockIdx.x;
  const int tid = threadIdx.x, lane = tid & 63;
  int job, rel;
  if (bid < 8192)       { job = 0; rel = bid; }
  else if (bid < 10240) { job = 1; rel = bid - 8192; }
  else if (bid < 11264) { job = 2; rel = bid - 10240; }
  else if (bid < 13312) { job = 3; rel = bid - 11264; }
  else                  { job = 4; rel = bid - 13312; }
  const float* src_base; int ld, S, NH, soff, st;
  const float* nw = nullptr; const float* cosT = nullptr; const float* sinT = nullptr;
  unsigned short* dst; float premul = 1.f; bool dorope;
  switch (job) {
    case 0: src_base = qkvC;        ld = 3072; S = 1024; NH = 16; soff = 0;    st = 1024;
            nw = q_norm_w;       cosT = img_cos; sinT = img_sin; dst = qb;   premul = scale; dorope = true;  break;
    case 1: src_base = qkvC + 2048; ld = 3072; S = 1024; NH = 4;  soff = 0;    st = 1536;
            nw = k_norm_w;       cosT = img_cos; sinT = img_sin; dst = kbuf;                 dorope = true;  break;
    case 2: src_base = kvtC;        ld = 1024; S = 512;  NH = 4;  soff = 1024; st = 1536;
            nw = added_k_norm_w; cosT = txt_cos; sinT = txt_sin; dst = kbuf;                 dorope = true;  break;
    case 3: src_base = qkvC + 2560; ld = 3072; S = 1024; NH = 4;  soff = 0;    st = 1536;
            dst = vbuf; dorope = false; break;
    default:src_base = kvtC + 512;  ld = 1024; S = 512;  NH = 4;  soff = 1024; st = 1536;
            dst = vbuf; dorope = false; break;
  }
  int rowid = rel * 4 + (tid >> 6);
  int b = rowid / (S * NH);
  int rem = rowid % (S * NH);
  int s = rem / NH, h = rem % NH;
  const float* src = src_base + (size_t)(b * S + s) * ld + h * 128;
  float2 xv = *(const float2*)&src[lane * 2];
  float orr, oi;
  if (dorope) {
    float ss = xv.x * xv.x + xv.y * xv.y;
    #pragma unroll
    for (int off = 1; off < 64; off <<= 1) ss += __shfl_xor(ss, off);
    float inv = rsqrtf(ss * (1.f / 128.f) + 1e-6f);
    float yr = xv.x * inv * nw[lane * 2];
    float yi = xv.y * inv * nw[lane * 2 + 1];
    float c  = cosT[s * 64 + lane], sn = sinT[s * 64 + lane];
    orr = (yr * c - yi * sn) * premul;
    oi  = (yr * sn + yi * c) * premul;
  } else {
    orr = xv.x; oi = xv.y;
  }
  unsigned short* d = dst + ((size_t)(b * NH + h) * st + (s + soff)) * 128;
  d[lane * 2]     = f2bf(orr);
  d[lane * 2 + 1] = f2bf(oi);
}

// ---------------------------------------------------------------------------
// Flash attention: 128 q-rows/block (8 waves x 16 rows), Sk tiles of 64.
// XOR-swizzled LDS + async dbuf reg staging + setprio. Grid 256 (1/CU).
// ---------------------------------------------------------------------------
__global__ __launch_bounds__(512) void attn_kernel(
    const unsigned short* __restrict__ q,
    const unsigned short* __restrict__ kbuf,
    const unsigned short* __restrict__ vbuf,
    unsigned short* __restrict__ o)
{
  const int SK = 1536;
  const int w = xcd_swz(blockIdx.x, gridDim.x);
  const int bh = w >> 3;
  const int b = bh >> 4, h = bh & 15, kvh = h >> 2;
  const int q0 = (w & 7) * 128;
  const int tid = threadIdx.x, lane = tid & 63, wid = tid >> 6;
  const int l16 = lane & 15, kb = (lane >> 4) * 8, r4 = (lane >> 4) * 4;
  __shared__ unsigned short KsL[64 * 128];
  __shared__ unsigned short VTL[128 * 64];
  __shared__ unsigned short PsL[8 * 16 * 64];
  const int sr0 = tid >> 4;          // 0..31
  const int scc = (tid & 15) * 8;

  const unsigned short* qrow =
      q + ((size_t)(b * 16 + h) * 1024 + q0 + wid * 16 + l16) * 128;
  bf16x8 qf[4];
  #pragma unroll
  for (int ks = 0; ks < 4; ++ks) qf[ks] = *(const bf16x8*)&qrow[ks * 32 + kb];
  float mrow[4] = {-1e30f, -1e30f, -1e30f, -1e30f};
  float lrow[4] = {0.f, 0.f, 0.f, 0.f};
  f32x4 oacc[8] = {};
  const unsigned short* kb_base = kbuf + (size_t)(b * 4 + kvh) * SK * 128;
  const unsigned short* vb_base = vbuf + (size_t)(b * 4 + kvh) * SK * 128;

  u16x8 k0[2], v0[2], k1[2], v1[2];

#define ATT_LOAD(kr, vr, kt1)                                                 \
  {                                                                           \
    _Pragma("unroll")                                                         \
    for (int i = 0; i < 2; ++i) {                                             \
      kr[i] = *(const u16x8*)&kb_base[(size_t)((kt1) + sr0 + 32 * i) * 128 + scc]; \
      vr[i] = *(const u16x8*)&vb_base[(size_t)((kt1) + sr0 + 32 * i) * 128 + scc]; \
    }                                                                         \
  }

#define ATT_STAGE(kr, vr)                                                     \
  {                                                                           \
    _Pragma("unroll")                                                         \
    for (int i = 0; i < 2; ++i) {                                             \
      int rr = sr0 + 32 * i;                                                  \
      *(u16x8*)&KsL[rr * 128 + (((scc >> 3) ^ (rr & 7)) << 3)] = kr[i];       \
      _Pragma("unroll")                                                       \
      for (int j = 0; j < 8; ++j)                                             \
        VTL[(scc + j) * 64 + ((((rr >> 3) ^ ((scc + j) >> 3)) & 7) << 3) + (rr & 7)] = vr[i][j]; \
    }                                                                         \
  }

  auto compute = [&]() {
    f32x4 sacc[4] = {};
    __builtin_amdgcn_s_setprio(1);
    #pragma unroll
    for (int ks = 0; ks < 4; ++ks) {
      #pragma unroll
      for (int ni = 0; ni < 4; ++ni) {
        int rr = ni * 16 + l16;
        bf16x8 kf = *(const bf16x8*)
            &KsL[rr * 128 + ((((ks * 32 + kb) >> 3) ^ (rr & 7)) << 3)];
        sacc[ni] = __builtin_amdgcn_mfma_f32_16x16x32_bf16(qf[ks], kf, sacc[ni], 0, 0, 0);
      }
    }
    __builtin_amdgcn_s_setprio(0);
    float pv[4][4], alpha[4];
    #pragma unroll
    for (int r = 0; r < 4; ++r) {
      float tm = fmaxf(fmaxf(sacc[0][r], sacc[1][r]), fmaxf(sacc[2][r], sacc[3][r]));
      #pragma unroll
      for (int off = 1; off < 16; off <<= 1) tm = fmaxf(tm, __shfl_xor(tm, off));
      float mn = fmaxf(mrow[r], tm);
      alpha[r] = __expf(mrow[r] - mn);
      float s = 0.f;
      #pragma unroll
      for (int ni = 0; ni < 4; ++ni) {
        float p = __expf(sacc[ni][r] - mn);
        pv[ni][r] = p; s += p;
      }
      #pragma unroll
      for (int off = 1; off < 16; off <<= 1) s += __shfl_xor(s, off);
      lrow[r] = lrow[r] * alpha[r] + s;
      mrow[r] = mn;
    }
    #pragma unroll
    for (int ni = 0; ni < 8; ++ni)
      #pragma unroll
      for (int r = 0; r < 4; ++r) oacc[ni][r] *= alpha[r];
    #pragma unroll
    for (int ni = 0; ni < 4; ++ni)
      #pragma unroll
      for (int r = 0; r < 4; ++r) {
        int row = r4 + r, col = ni * 16 + l16;
        PsL[wid * 1024 + row * 64 + ((((col >> 3) ^ (row & 7)) & 7) << 3) + (col & 7)]
            = f2bf(pv[ni][r]);
      }
    asm volatile("s_waitcnt lgkmcnt(0)" ::: "memory");
    __builtin_amdgcn_sched_barrier(0);
    __builtin_amdgcn_s_setprio(1);
    #pragma unroll
    for (int ks = 0; ks < 2; ++ks) {
      bf16x8 pf = *(const bf16x8*)
          &PsL[wid * 1024 + l16 * 64 + ((((ks * 32 + kb) >> 3) ^ (l16 & 7)) << 3)];
      #pragma unroll
      for (int ni = 0; ni < 8; ++ni) {
        int d = ni * 16 + l16;
        bf16x8 vf = *(const bf16x8*)
            &VTL[d * 64 + ((((ks * 32 + kb) >> 3) ^ ((d >> 3) & 7)) << 3)];
        oacc[ni] = __builtin_amdgcn_mfma_f32_16x16x32_bf16(pf, vf, oacc[ni], 0, 0, 0);
      }
    }
    __builtin_amdgcn_s_setprio(0);
  };

  ATT_LOAD(k0, v0, 0);
  for (int t = 0; t < 24; t += 2) {
    ATT_STAGE(k0, v0);
    ATT_LOAD(k1, v1, (t + 1) * 64);
    asm volatile("s_waitcnt lgkmcnt(0)" ::: "memory");
    __builtin_amdgcn_s_barrier();
    __builtin_amdgcn_sched_barrier(0);
    compute();
    __builtin_amdgcn_sched_barrier(0);
    __builtin_amdgcn_s_barrier();
    ATT_STAGE(k1, v1);
    if (t + 2 < 24) ATT_LOAD(k0, v0, (t + 2) * 64);
    asm volatile("s_waitcnt lgkmcnt(0)" ::: "memory");
    __builtin_amdgcn_s_barrier();
    __builtin_amdgcn_sched_barrier(0);
    compute();
    __builtin_amdgcn_sched_barrier(0);
    __builtin_amdgcn_s_barrier();
  }
#undef ATT_LOAD
#undef ATT_STAGE

  #pragma unroll
  for (int ni = 0; ni < 8; ++ni)
    #pragma unroll
    for (int r = 0; r < 4; ++r) {
      float val = oacc[ni][r] / lrow[r];
      size_t row = (size_t)b * 1024 + q0 + wid * 16 + r4 + r;
      o[row * 2048 + h * 128 + ni * 16 + l16] = f2bf(val);
    }
}

__global__ void scan_offsets(const int* __restrict__ counts, int* __restrict__ offsets)
{
  if (threadIdx.x == 0 && blockIdx.x == 0) {
    int a = 0;
    for (int e = 0; e < 8; ++e) { offsets[e] = a; a += counts[e]; }
    offsets[8] = a;
  }
}

__global__ __launch_bounds__(256) void scatter_pairs(
    const int* __restrict__ topi, const int* __restrict__ offsets,
    int* __restrict__ fill, int* __restrict__ pair_token, int* __restrict__ token_slot)
{
  int t = blockIdx.x * 256 + threadIdx.x;
  if (t >= 2048) return;
  #pragma unroll
  for (int k = 0; k < 2; ++k) {
    int e = topi[2 * t + k];
    int slot = offsets[e] + atomicAdd(&fill[e], 1);
    pair_token[slot] = t;
    token_slot[2 * t + k] = slot;
  }
}

// act_silu over summed split-K partials: g/u = gu0 + gu1.
__global__ __launch_bounds__(256) void act_silu2(
    const float* __restrict__ gu0, const float* __restrict__ gu1,
    unsigned short* __restrict__ act)
{
  int p = blockIdx.x;
  int c = threadIdx.x * 4;
  float4 g0 = *(const float4*)&gu0[(size_t)p * 2048 + c];
  float4 g1 = *(const float4*)&gu1[(size_t)p * 2048 + c];
  float4 u0 = *(const float4*)&gu0[(size_t)p * 2048 + 1024 + c];
  float4 u1 = *(const float4*)&gu1[(size_t)p * 2048 + 1024 + c];
  float gg[4] = {g0.x + g1.x, g0.y + g1.y, g0.z + g1.z, g0.w + g1.w};
  float uu[4] = {u0.x + u1.x, u0.y + u1.y, u0.z + u1.z, u0.w + u1.w};
  #pragma unroll
  for (int j = 0; j < 4; ++j) {
    float a = gg[j] / (1.f + __expf(-gg[j])) * uu[j];
    act[(size_t)p * 1024 + c + j] = f2bf(a);
  }
}

// combine over summed split-K partials: eo = eo0 + eo1.
__global__ __launch_bounds__(256) void moe_combine2(
    float* __restrict__ out, const float* __restrict__ eo0,
    const float* __restrict__ eo1,
    const int* __restrict__ token_slot, const float* __restrict__ topw)
{
  int t = blockIdx.x;
  int c = threadIdx.x * 8;
  int s0 = token_slot[2 * t], s1 = token_slot[2 * t + 1];
  float w0 = topw[2 * t], w1 = topw[2 * t + 1];
  #pragma unroll
  for (int j0 = 0; j0 < 8; j0 += 4) {
    float4 a0 = *(const float4*)&eo0[(size_t)s0 * 2048 + c + j0];
    float4 a1 = *(const float4*)&eo1[(size_t)s0 * 2048 + c + j0];
    float4 b0 = *(const float4*)&eo0[(size_t)s1 * 2048 + c + j0];
    float4 b1 = *(const float4*)&eo1[(size_t)s1 * 2048 + c + j0];
    float4 v = *(const float4*)&out[(size_t)t * 2048 + c + j0];
    v.x += w0 * (a0.x + a1.x) + w1 * (b0.x + b1.x);
    v.y += w0 * (a0.y + a1.y) + w1 * (b0.y + b1.y);
    v.z += w0 * (a0.z + a1.z) + w1 * (b0.z + b1.z);
    v.w += w0 * (a0.w + a1.w) + w1 * (b0.w + b1.w);
    *(float4*)&out[(size_t)t * 2048 + c + j0] = v;
  }
}

// ---------------------------------------------------------------------------
extern "C" void kernel_launch(void* const* d_in, const int* in_sizes, int n_in,
                              void* d_out, int out_size, void* d_ws, size_t ws_size,
                              hipStream_t stream)
{
  const float* hidden  = (const float*)d_in[0];
  const float* enc     = (const float*)d_in[1];
  const float* img_cos = (const float*)d_in[2];
  const float* img_sin = (const float*)d_in[3];
  const float* txt_cos = (const float*)d_in[4];
  const float* txt_sin = (const float*)d_in[5];
  const float* norm1_w = (const float*)d_in[6];
  const float* norm2_w = (const float*)d_in[7];
  const float* wq      = (const float*)d_in[8];
  const float* wk      = (const float*)d_in[9];
  const float* wv      = (const float*)d_in[10];
  const float* wk_txt  = (const float*)d_in[11];
  const float* wv_txt  = (const float*)d_in[12];
  const float* wo      = (const float*)d_in[13];
  const float* q_norm_w       = (const float*)d_in[14];
  const float* k_norm_w       = (const float*)d_in[15];
  const float* added_k_norm_w = (const float*)d_in[16];
  const float* router_w       = (const float*)d_in[17];
  const float* gate_up_proj   = (const float*)d_in[18];
  const float* down_proj      = (const float*)d_in[19];
  float* out = (float*)d_out;

  char* ws = (char*)d_ws;
  size_t off = 0;
  auto alloc = [&](size_t bytes) {
    void* p = ws + off;
    off += (bytes + 255) & ~(size_t)255;
    return p;
  };
  // --- bf16 transposed weights ---
  unsigned short* wqkvT  = (unsigned short*)alloc(3072ULL * 2048 * 2); // q|k|v rows
  unsigned short* wkvtT  = (unsigned short*)alloc(1024ULL * 2048 * 2); // k_txt|v_txt
  unsigned short* woT    = (unsigned short*)alloc(2048ULL * 2048 * 2);
  unsigned short* gupT   = (unsigned short*)alloc(8ULL * 2048 * 2048 * 2);
  unsigned short* dnT    = (unsigned short*)alloc(8ULL * 2048 * 1024 * 2);
  // --- activations ---
  unsigned short* x_bf   = (unsigned short*)alloc(2048ULL * 2048 * 2);
  unsigned short* enc_bf = (unsigned short*)alloc(1024ULL * 2048 * 2);
  float* qkvC = (float*)alloc(4096ULL * 2048 * 4); // [2048][3072] early; partial-0 late
  float* gu0  = qkvC;                              // alias (disjoint lifetimes)
  float* gu1  = (float*)alloc(4096ULL * 2048 * 4); // partial-1
  float* kvtC = (float*)alloc(1024ULL * 1024 * 4); // [1024][1024] k_txt|v_txt
  unsigned short* qb   = (unsigned short*)alloc(2048ULL * 2048 * 2);
  unsigned short* kbuf = (unsigned short*)alloc(2ULL * 4 * 1536 * 128 * 2);
  unsigned short* vbuf = (unsigned short*)alloc(2ULL * 4 * 1536 * 128 * 2);
  unsigned short* obuf = (unsigned short*)alloc(2048ULL * 2048 * 2);
  unsigned short* act  = obuf;                     // alias (obuf dead after wo GEMM)
  unsigned short* xt   = (unsigned short*)alloc(2048ULL * 2048 * 2);
  int*   ctrl  = (int*)alloc(64 * sizeof(int));    // counts[8] fill[8] offsets[9]
  int*   topi  = (int*)alloc(4096 * 4);
  float* topw  = (float*)alloc(4096 * 4);
  int*   tslot = (int*)alloc(4096 * 4);
  int*   ptok  = (int*)alloc(4096 * 4);
  unsigned short* zbuf = (unsigned short*)alloc(256);
  int* counts = ctrl, * fill = ctrl + 8, * offsets = ctrl + 16;

  hipMemsetAsync(ctrl, 0, 64, stream);
  hipMemsetAsync(zbuf, 0, 256, stream);

  const float scale = 0.08838834764831845f;  // 1/sqrt(128)

  // --- batched weight preprocessing: f32 [K][N] -> bf16 [N][K] ---
  CvtJobs jb;
  jb.src[0] = wq;     jb.dst[0] = wqkvT;                  jb.K[0] = 2048; jb.N[0] = 2048;
  jb.src[1] = wk;     jb.dst[1] = wqkvT + 2048ULL * 2048; jb.K[1] = 2048; jb.N[1] = 512;
  jb.src[2] = wv;     jb.dst[2] = wqkvT + 2560ULL * 2048; jb.K[2] = 2048; jb.N[2] = 512;
  jb.src[3] = wk_txt; jb.dst[3] = wkvtT;                  jb.K[3] = 2048; jb.N[3] = 512;
  jb.src[4] = wv_txt; jb.dst[4] = wkvtT + 512ULL * 2048;  jb.K[4] = 2048; jb.N[4] = 512;
  jb.src[5] = wo;     jb.dst[5] = woT;                    jb.K[5] = 2048; jb.N[5] = 2048;
  jb.src[6] = gate_up_proj; jb.dst[6] = gupT;             jb.K[6] = 2048; jb.N[6] = 2048;
  jb.src[7] = down_proj;    jb.dst[7] = dnT;              jb.K[7] = 1024; jb.N[7] = 2048;
  // blocks: 1024, 256, 256, 256, 256, 1024, 8*1024=8192, 8*512=4096
  jb.off[0] = 0;     jb.off[1] = 1024;  jb.off[2] = 1280; jb.off[3] = 1536;
  jb.off[4] = 1792;  jb.off[5] = 2048;  jb.off[6] = 3072; jb.off[7] = 11264;
  jb.off[8] = 15360;
  convert_all<<<15360, 256, 0, stream>>>(jb);

  rmsnorm_rows<<<2048, 256, 0, stream>>>(hidden, norm1_w, x_bf);
  f32_to_bf16_k<<<2048, 256, 0, stream>>>(enc, enc_bf, 1024 * 2048);

  // fused qkv projection: [2048][2048] @ [3072][2048]^T -> [2048][3072]
  gemm_bb<<<384, 256, 0, stream>>>(x_bf, wqkvT, qkvC, nullptr, 2048, 3072, 2048);
  // fused k/v txt projection: [1024][2048] @ [1024][2048]^T -> [1024][1024]
  gemm_bb<<<64, 256, 0, stream>>>(enc_bf, wkvtT, kvtC, nullptr, 1024, 1024, 2048);

  prep_all<<<14336, 256, 0, stream>>>(qkvC, kvtC, q_norm_w, k_norm_w, added_k_norm_w,
                                      img_cos, img_sin, txt_cos, txt_sin,
                                      qb, kbuf, vbuf, scale);

  attn_kernel<<<256, 512, 0, stream>>>(qb, kbuf, vbuf, obuf);

  gemm_bb<<<256, 256, 0, stream>>>(obuf, woT, out, hidden, 2048, 2048, 2048);

  rmsnorm_router<<<2048, 256, 0, stream>>>(out, norm2_w, xt, router_w,
                                           topi, topw, counts);
  scan_offsets<<<1, 64, 0, stream>>>(counts, offsets);
  scatter_pairs<<<8, 256, 0, stream>>>(topi, offsets, fill, ptok, tslot);

  // gate_up: split-K=2 into gu0/gu1
  gemm_moe_256sk<<<1024, 512, 0, stream>>>(xt, gupT, gu0, gu1,
                                           counts, offsets, ptok, zbuf, 1, 2048, 2048);
  act_silu2<<<4096, 256, 0, stream>>>(gu0, gu1, act);
  // down: split-K=2 into gu0/gu1 (reused as eo partials)
  gemm_moe_256sk<<<1024, 512, 0, stream>>>(act, dnT, gu0, gu1,
                                           counts, offsets, ptok, zbuf, 0, 1024, 2048);
  moe_combine2<<<2048, 256, 0, stream>>>(out, gu0, gu1, tslot, topw);
}

// Round 13
// 558.721 us; speedup vs baseline: 1.1692x; 1.0075x over previous
//
#include <hip/hip_runtime.h>

// ---------------------------------------------------------------------------
// NucleusMoEImageTransformerBlock round 13.
// B=2 SI=1024 ST=512 D=2048 H=16 KV=4 HD=128 E=8 F=1024 TOPK=2
// Round-13: fuse head-RMSNorm + RoPE + relayout into the qkv/kvt GEMM
// epilogues (each 128-wide N-tile == one head; row-SS via shfl + tiny LDS
// exchange; rope pair via shfl_xor(1)). Eliminates prep_all and the
// qkvC/kvtC f32 round-trip (~70 MB + 1 launch). wo GEMM keeps f32+resid.
// convert_all measured at ~83% of streaming roofline -- left as is.
// ---------------------------------------------------------------------------

typedef __attribute__((ext_vector_type(8))) __bf16 bf16x8;
typedef __attribute__((ext_vector_type(8))) unsigned short u16x8;
typedef __attribute__((ext_vector_type(4))) float f32x4;

__device__ __forceinline__ unsigned short f2bf(float x) {
  unsigned u = __builtin_bit_cast(unsigned, x);
  u += 0x7fffu + ((u >> 16) & 1u);        // RNE
  return (unsigned short)(u >> 16);
}
__device__ __forceinline__ float bf2f(unsigned short b) {
  return __builtin_bit_cast(float, ((unsigned)b) << 16);
}

__device__ __forceinline__ void glds16(const unsigned short* g, unsigned short* l) {
  __builtin_amdgcn_global_load_lds(
      (const __attribute__((address_space(1))) void*)g,
      (__attribute__((address_space(3))) void*)l, 16, 0, 0);
}

// m204 bijective XCD chunk swizzle.
__device__ __forceinline__ int xcd_swz(int orig, int nwg) {
  int q = nwg >> 3, r = nwg & 7;
  int xcd = orig & 7, idx = orig >> 3;
  int base = (xcd < r) ? xcd * (q + 1) : r * (q + 1) + (xcd - r) * q;
  return base + idx;
}

// ---------------------------------------------------------------------------
// Batched weight convert+transpose: 8 jobs, W f32 [K][N] -> WT bf16 [N][K].
// ---------------------------------------------------------------------------
struct CvtJobs {
  const float* src[8];
  unsigned short* dst[8];
  int K[8];
  int N[8];
  int off[9];
};

__global__ __launch_bounds__(256) void convert_all(CvtJobs jb)
{
  __shared__ unsigned short T[64][66];
  const int bid = blockIdx.x;
  int j = 0;
  #pragma unroll
  for (int i = 0; i < 8; ++i) if (bid >= jb.off[i + 1]) j = i + 1;
  const int local = bid - jb.off[j];
  const int K = jb.K[j], N = jb.N[j];
  const int kb = K >> 6, nb = N >> 6;
  const int kt = local % kb;
  const int rest = local / kb;
  const int nt = rest % nb, zi = rest / nb;
  const float* Wz = jb.src[j] + (size_t)zi * K * N;
  unsigned short* WTz = jb.dst[j] + (size_t)zi * K * N;
  const int k0 = kt * 64, n0 = nt * 64;
  const int tid = threadIdx.x;
  #pragma unroll
  for (int i = tid; i < 64 * 16; i += 256) {
    int k = i >> 4, n4 = (i & 15) * 4;
    float4 v = *(const float4*)&Wz[(size_t)(k0 + k) * N + n0 + n4];
    T[n4 + 0][k] = f2bf(v.x);
    T[n4 + 1][k] = f2bf(v.y);
    T[n4 + 2][k] = f2bf(v.z);
    T[n4 + 3][k] = f2bf(v.w);
  }
  __syncthreads();
  #pragma unroll
  for (int i = tid; i < 64 * 8; i += 256) {
    int n = i >> 3, k8 = (i & 7) * 8;
    *(u16x8*)&WTz[(size_t)(n0 + n) * K + k0 + k8] = *(const u16x8*)&T[n][k8];
  }
}

// ---------------------------------------------------------------------------
// Epilogue argument bundle for gemm_bb modes 1/2.
// ---------------------------------------------------------------------------
struct Epi {
  unsigned short* qb;
  unsigned short* kbuf;
  unsigned short* vbuf;
  const float* q_nw;
  const float* k_nw;
  const float* kt_nw;
  const float* icos;
  const float* isin;
  const float* tcos;
  const float* tsin;
  float scale;
};

// ---------------------------------------------------------------------------
// Dense GEMM: acc = A[M,K] @ BT[N,K]^T (bf16 in, f32 acc).
// mode 0: C = acc (+resid), f32.
// mode 1 (qkv, M=2048): N-tile bt<16 -> Q head (norm+rope+scale -> qb);
//   bt in [16,20) -> K_img head (norm+rope -> kbuf); else V_img -> vbuf.
// mode 2 (kvt, M=1024): bt<4 -> K_txt (norm+rope, soff=1024); else V_txt.
// 128x128 tile, counted-vmcnt dbuf pipeline.
// ---------------------------------------------------------------------------
__global__ __launch_bounds__(256) void gemm_bb(
    const unsigned short* __restrict__ A, const unsigned short* __restrict__ BT,
    float* __restrict__ C, const float* __restrict__ resid,
    int M, int N, int K, int mode, Epi ep)
{
  __shared__ unsigned short As[2][128 * 64];
  __shared__ unsigned short Bs[2][128 * 64];
  const int mb = M >> 7;
  const int w = xcd_swz(blockIdx.x, gridDim.x);
  const int bm = (w % mb) * 128, bn = (w / mb) * 128;
  const int tid = threadIdx.x, lane = tid & 63, wid = tid >> 6;
  const int wm = (wid >> 1) * 64, wn = (wid & 1) * 64;
  const int l16 = lane & 15, g4 = lane >> 4;
  const int rseg = lane >> 3;
  const int csw  = ((lane & 7) ^ rseg) * 8;
  const unsigned short* aSrc[4];
  const unsigned short* bSrc[4];
  #pragma unroll
  for (int p = 0; p < 4; ++p) {
    int row = (p * 4 + wid) * 8 + rseg;
    aSrc[p] = A  + (size_t)(bm + row) * K + csw;
    bSrc[p] = BT + (size_t)(bn + row) * K + csw;
  }
  f32x4 acc[4][4] = {};
  const int NT = K >> 6;
  #pragma unroll
  for (int p = 0; p < 4; ++p) glds16(aSrc[p], &As[0][(p * 4 + wid) * 512]);
  #pragma unroll
  for (int p = 0; p < 4; ++p) glds16(bSrc[p], &Bs[0][(p * 4 + wid) * 512]);
  for (int t = 0; t < NT; ++t) {
    const int cur = t & 1;
    if (t + 1 < NT) {
      const int k0 = (t + 1) << 6;
      #pragma unroll
      for (int p = 0; p < 4; ++p) glds16(aSrc[p] + k0, &As[cur ^ 1][(p * 4 + wid) * 512]);
      #pragma unroll
      for (int p = 0; p < 4; ++p) glds16(bSrc[p] + k0, &Bs[cur ^ 1][(p * 4 + wid) * 512]);
      asm volatile("s_waitcnt vmcnt(8)" ::: "memory");
    } else {
      asm volatile("s_waitcnt vmcnt(0)" ::: "memory");
    }
    __builtin_amdgcn_s_barrier();
    __builtin_amdgcn_sched_barrier(0);
    const unsigned short* ab = &As[cur][0];
    const unsigned short* bb = &Bs[cur][0];
    #pragma unroll
    for (int ks = 0; ks < 2; ++ks) {
      bf16x8 af[4], bf[4];
      #pragma unroll
      for (int i = 0; i < 4; ++i) {
        int ra = wm + i * 16 + l16;
        int rb = wn + i * 16 + l16;
        int ch = ((ks * 4 + g4) ^ (l16 & 7)) * 8;
        af[i] = *(const bf16x8*)&ab[ra * 64 + ch];
        bf[i] = *(const bf16x8*)&bb[rb * 64 + ch];
      }
      #pragma unroll
      for (int mi = 0; mi < 4; ++mi)
        #pragma unroll
        for (int ni = 0; ni < 4; ++ni)
          acc[mi][ni] = __builtin_amdgcn_mfma_f32_16x16x32_bf16(af[mi], bf[ni], acc[mi][ni], 0, 0, 0);
    }
    __builtin_amdgcn_sched_barrier(0);
    __builtin_amdgcn_s_barrier();
  }
  const int r4 = g4 * 4;

  if (mode == 0) {
    #pragma unroll
    for (int mi = 0; mi < 4; ++mi)
      #pragma unroll
      for (int ni = 0; ni < 4; ++ni)
        #pragma unroll
        for (int r = 0; r < 4; ++r) {
          int row = bm + wm + mi * 16 + r4 + r;
          int col = bn + wn + ni * 16 + l16;
          float v = acc[mi][ni][r];
          if (resid) v += resid[(size_t)row * N + col];
          C[(size_t)row * N + col] = v;
        }
    return;
  }

  // ---- fused head-norm / rope / relayout epilogue (modes 1,2) ----
  const int bt = bn >> 7;               // 128-wide tile == one head
  unsigned short* dst;
  const float* nw = nullptr;
  const float* cosT = nullptr;
  const float* sinT = nullptr;
  int h, NH, st, soff, vkind = 0, shift;
  float premul = 1.f;
  int S;
  if (mode == 1) {
    S = 1024; shift = 10;
    if (bt < 16)      { h = bt;      dst = ep.qb;   nw = ep.q_nw; cosT = ep.icos; sinT = ep.isin;
                        NH = 16; st = 1024; soff = 0; premul = ep.scale; }
    else if (bt < 20) { h = bt - 16; dst = ep.kbuf; nw = ep.k_nw; cosT = ep.icos; sinT = ep.isin;
                        NH = 4;  st = 1536; soff = 0; }
    else              { h = bt - 20; dst = ep.vbuf; vkind = 1; NH = 4; st = 1536; soff = 0; }
  } else {
    S = 512; shift = 9;
    if (bt < 4) { h = bt;     dst = ep.kbuf; nw = ep.kt_nw; cosT = ep.tcos; sinT = ep.tsin;
                  NH = 4; st = 1536; soff = 1024; }
    else        { h = bt - 4; dst = ep.vbuf; vkind = 1; NH = 4; st = 1536; soff = 1024; }
  }

  if (vkind) {
    #pragma unroll
    for (int mi = 0; mi < 4; ++mi)
      #pragma unroll
      for (int ni = 0; ni < 4; ++ni)
        #pragma unroll
        for (int r = 0; r < 4; ++r) {
          int row = wm + mi * 16 + r4 + r;
          int d   = wn + ni * 16 + l16;
          int token = bm + row;
          int srow = token & (S - 1), bidx = token >> shift;
          dst[((size_t)(bidx * NH + h) * st + srow + soff) * 128 + d] = f2bf(acc[mi][ni][r]);
        }
    return;
  }

  // row sum-of-squares: per-lane partial over this wave's 4 ni columns,
  // shfl-reduce over 16 lanes, cross-wave exchange via LDS (reuse As).
  float* ssb = (float*)&As[0][0];       // [2 col-halves][128 rows]
  float ssp[4][4];
  #pragma unroll
  for (int mi = 0; mi < 4; ++mi)
    #pragma unroll
    for (int r = 0; r < 4; ++r) {
      float v = 0.f;
      #pragma unroll
      for (int ni = 0; ni < 4; ++ni) v += acc[mi][ni][r] * acc[mi][ni][r];
      #pragma unroll
      for (int off = 1; off < 16; off <<= 1) v += __shfl_xor(v, off);
      ssp[mi][r] = v;
    }
  __syncthreads();
  if (l16 == 0) {
    #pragma unroll
    for (int mi = 0; mi < 4; ++mi)
      #pragma unroll
      for (int r = 0; r < 4; ++r)
        ssb[(wid & 1) * 128 + wm + mi * 16 + r4 + r] = ssp[mi][r];
  }
  __syncthreads();
  #pragma unroll
  for (int mi = 0; mi < 4; ++mi)
    #pragma unroll
    for (int r = 0; r < 4; ++r) {
      int row = wm + mi * 16 + r4 + r;
      float tot = ssb[row] + ssb[128 + row];
      float inv = rsqrtf(tot * (1.f / 128.f) + 1e-6f);
      int token = bm + row;
      int srow = token & (S - 1), bidx = token >> shift;
      #pragma unroll
      for (int ni = 0; ni < 4; ++ni) {
        int d = wn + ni * 16 + l16;
        float y = acc[mi][ni][r] * inv * nw[d];
        float part = __shfl_xor(y, 1);
        float c  = cosT[srow * 64 + (d >> 1)];
        float sn = sinT[srow * 64 + (d >> 1)];
        float outv = (d & 1) ? (part * sn + y * c) : (y * c - part * sn);
        dst[((size_t)(bidx * NH + h) * st + srow + soff) * 128 + d] = f2bf(outv * premul);
      }
    }
}

// ---------------------------------------------------------------------------
// Expert-batched MoE GEMM, 256x256 tile, split-K=2. Grid 1024 = 8bm x 2kh x
// 8bn x 8e, XCD-swizzled -> one expert per XCD.
// ---------------------------------------------------------------------------
__global__ __launch_bounds__(512, 1) void gemm_moe_256sk(
    const unsigned short* __restrict__ A, const unsigned short* __restrict__ BTall,
    float* __restrict__ C0, float* __restrict__ C1,
    const int* __restrict__ counts, const int* __restrict__ offsets,
    const int* __restrict__ pair_token, const unsigned short* __restrict__ zbuf,
    int gather, int K, int N)
{
  const int w = xcd_swz(blockIdx.x, gridDim.x);
  const int e = w >> 7;
  const int local = w & 127;
  const int bm = ((local >> 4) & 7) * 256;
  const int kh = (local >> 3) & 1;
  const int bn = (local & 7) * 256;
  const int cnt = counts[e];
  if (bm >= cnt) return;
  const int base = offsets[e];
  const int Kh = K >> 1;
  float* __restrict__ C = kh ? C1 : C0;
  __shared__ unsigned short As[256 * 64];
  __shared__ unsigned short Bs[256 * 64];
  __shared__ int rowmap[256];
  const int tid = threadIdx.x, lane = tid & 63, wid = tid >> 6;
  const int wr = wid >> 2, wc = wid & 3;
  const int l16 = lane & 15, g4 = lane >> 4;
  const int rseg = lane >> 3;
  const int csw  = ((lane & 7) ^ rseg) * 8;
  if (tid < 256) {
    int lr = bm + tid;
    rowmap[tid] = (lr < cnt) ? (gather ? pair_token[base + lr] : base + lr) : -1;
  }
  __syncthreads();
  const unsigned short* BT = BTall + (size_t)e * N * K;
  const unsigned short* aSrc[4];
  const unsigned short* bSrc[4];
  int aOk[4];
  #pragma unroll
  for (int p = 0; p < 4; ++p) {
    int row = (p * 8 + wid) * 8 + rseg;
    int tok = rowmap[row];
    aOk[p] = (tok >= 0);
    aSrc[p] = aOk[p] ? (A + (size_t)tok * K + kh * Kh + csw) : (zbuf + csw);
    bSrc[p] = BT + (size_t)(bn + row) * K + kh * Kh + csw;
  }
  f32x4 acc[8][4] = {};
  const int NT = Kh >> 6;
  for (int t = 0; t < NT; ++t) {
    const int k0 = t << 6;
    #pragma unroll
    for (int p = 0; p < 4; ++p)
      glds16(aSrc[p] + (aOk[p] ? k0 : 0), &As[(p * 8 + wid) * 512]);
    #pragma unroll
    for (int p = 0; p < 4; ++p)
      glds16(bSrc[p] + k0, &Bs[(p * 8 + wid) * 512]);
    __syncthreads();
    #pragma unroll
    for (int ks = 0; ks < 2; ++ks) {
      const int ch = ((ks * 4 + g4) ^ (l16 & 7)) * 8;
      bf16x8 bf[4];
      #pragma unroll
      for (int j = 0; j < 4; ++j)
        bf[j] = *(const bf16x8*)&Bs[(wc * 64 + j * 16 + l16) * 64 + ch];
      #pragma unroll
      for (int mi = 0; mi < 8; ++mi) {
        bf16x8 af = *(const bf16x8*)&As[(wr * 128 + mi * 16 + l16) * 64 + ch];
        #pragma unroll
        for (int ni = 0; ni < 4; ++ni)
          acc[mi][ni] = __builtin_amdgcn_mfma_f32_16x16x32_bf16(af, bf[ni], acc[mi][ni], 0, 0, 0);
      }
    }
    __syncthreads();
  }
  const int r4 = g4 * 4;
  #pragma unroll
  for (int mi = 0; mi < 8; ++mi)
    #pragma unroll
    for (int ni = 0; ni < 4; ++ni)
      #pragma unroll
      for (int r = 0; r < 4; ++r) {
        int lrow = bm + wr * 128 + mi * 16 + r4 + r;
        int col  = bn + wc * 64 + ni * 16 + l16;
        if (lrow < cnt)
          C[(size_t)(base + lrow) * N + col] = acc[mi][ni][r];
      }
}

// ---------------------------------------------------------------------------
// RMSNorm over D=2048, f32 in -> bf16 out. (norm1)
// ---------------------------------------------------------------------------
__global__ __launch_bounds__(256) void rmsnorm_rows(
    const float* __restrict__ in, const float* __restrict__ w,
    unsigned short* __restrict__ out)
{
  const int row = blockIdx.x;
  const int tid = threadIdx.x;
  const float* x = in + (size_t)row * 2048;
  float4 a = *(const float4*)&x[tid * 8];
  float4 b = *(const float4*)&x[tid * 8 + 4];
  float s = a.x*a.x + a.y*a.y + a.z*a.z + a.w*a.w
          + b.x*b.x + b.y*b.y + b.z*b.z + b.w*b.w;
  #pragma unroll
  for (int off = 1; off < 64; off <<= 1) s += __shfl_xor(s, off);
  __shared__ float red[4];
  if ((tid & 63) == 0) red[tid >> 6] = s;
  __syncthreads();
  float inv = rsqrtf((red[0] + red[1] + red[2] + red[3]) * (1.f / 2048.f) + 1e-6f);
  float4 wa = *(const float4*)&w[tid * 8];
  float4 wb = *(const float4*)&w[tid * 8 + 4];
  unsigned short* o = out + (size_t)row * 2048 + tid * 8;
  o[0] = f2bf(a.x * inv * wa.x); o[1] = f2bf(a.y * inv * wa.y);
  o[2] = f2bf(a.z * inv * wa.z); o[3] = f2bf(a.w * inv * wa.w);
  o[4] = f2bf(b.x * inv * wb.x); o[5] = f2bf(b.y * inv * wb.y);
  o[6] = f2bf(b.z * inv * wb.z); o[7] = f2bf(b.w * inv * wb.w);
}

// ---------------------------------------------------------------------------
// Fused RMSNorm(norm2) + router: bf16 xt out + exact-f32 top-2 routing.
// ---------------------------------------------------------------------------
__global__ __launch_bounds__(256) void rmsnorm_router(
    const float* __restrict__ in, const float* __restrict__ w,
    unsigned short* __restrict__ xt, const float* __restrict__ rw,
    int* __restrict__ topi, float* __restrict__ topw, int* __restrict__ counts)
{
  const int row = blockIdx.x;
  const int tid = threadIdx.x, lane = tid & 63, wid = tid >> 6;
  const float* x = in + (size_t)row * 2048;
  float4 a = *(const float4*)&x[tid * 8];
  float4 b = *(const float4*)&x[tid * 8 + 4];
  float s = a.x*a.x + a.y*a.y + a.z*a.z + a.w*a.w
          + b.x*b.x + b.y*b.y + b.z*b.z + b.w*b.w;
  #pragma unroll
  for (int off = 1; off < 64; off <<= 1) s += __shfl_xor(s, off);
  __shared__ float red[4];
  __shared__ float rl[4][8];
  if (lane == 0) red[wid] = s;
  __syncthreads();
  float inv = rsqrtf((red[0] + red[1] + red[2] + red[3]) * (1.f / 2048.f) + 1e-6f);
  float4 wa = *(const float4*)&w[tid * 8];
  float4 wb = *(const float4*)&w[tid * 8 + 4];
  float y[8] = {a.x * inv * wa.x, a.y * inv * wa.y, a.z * inv * wa.z, a.w * inv * wa.w,
                b.x * inv * wb.x, b.y * inv * wb.y, b.z * inv * wb.z, b.w * inv * wb.w};
  unsigned short* o = xt + (size_t)row * 2048 + tid * 8;
  #pragma unroll
  for (int j = 0; j < 8; ++j) o[j] = f2bf(y[j]);
  float lg[8] = {};
  #pragma unroll
  for (int j = 0; j < 8; ++j) {
    int d = tid * 8 + j;
    const float4 r0 = *(const float4*)&rw[d * 8];
    const float4 r1 = *(const float4*)&rw[d * 8 + 4];
    lg[0] += y[j] * r0.x; lg[1] += y[j] * r0.y; lg[2] += y[j] * r0.z; lg[3] += y[j] * r0.w;
    lg[4] += y[j] * r1.x; lg[5] += y[j] * r1.y; lg[6] += y[j] * r1.z; lg[7] += y[j] * r1.w;
  }
  #pragma unroll
  for (int e = 0; e < 8; ++e)
    #pragma unroll
    for (int off = 1; off < 64; off <<= 1) lg[e] += __shfl_xor(lg[e], off);
  if (lane == 0) {
    #pragma unroll
    for (int e = 0; e < 8; ++e) rl[wid][e] = lg[e];
  }
  __syncthreads();
  if (tid == 0) {
    float l[8];
    #pragma unroll
    for (int e = 0; e < 8; ++e) l[e] = rl[0][e] + rl[1][e] + rl[2][e] + rl[3][e];
    float v0 = l[0]; int e0 = 0;
    #pragma unroll
    for (int e = 1; e < 8; ++e) if (l[e] > v0) { v0 = l[e]; e0 = e; }
    float v1 = -1e30f; int e1 = 0;
    #pragma unroll
    for (int e = 0; e < 8; ++e) if (e != e0 && l[e] > v1) { v1 = l[e]; e1 = e; }
    float x1 = expf(v1 - v0);
    float w0 = 1.f / (1.f + x1);
    float w1 = x1 / (1.f + x1);
    topi[2 * row] = e0; topi[2 * row + 1] = e1;
    topw[2 * row] = w0; topw[2 * row + 1] = w1;
    atomicAdd(&counts[e0], 1);
    atomicAdd(&counts[e1], 1);
  }
}

__global__ __launch_bounds__(256) void f32_to_bf16_k(
    const float* __restrict__ in, unsigned short* __restrict__ out, int n)
{
  int i = (blockIdx.x * 256 + threadIdx.x) * 4;
  if (i + 3 < n) {
    float4 v = *(const float4*)&in[i];
    out[i + 0] = f2bf(v.x); out[i + 1] = f2bf(v.y);
    out[i + 2] = f2bf(v.z); out[i + 3] = f2bf(v.w);
  }
}

// ---------------------------------------------------------------------------
// Flash attention: 128 q-rows/block (8 waves x 16 rows), Sk tiles of 64.
// XOR-swizzled LDS + async dbuf reg staging + setprio. Grid 256 (1/CU).
// ---------------------------------------------------------------------------
__global__ __launch_bounds__(512) void attn_kernel(
    const unsigned short* __restrict__ q,
    const unsigned short* __restrict__ kbuf,
    const unsigned short* __restrict__ vbuf,
    unsigned short* __restrict__ o)
{
  const int SK = 1536;
  const int w = xcd_swz(blockIdx.x, gridDim.x);
  const int bh = w >> 3;
  const int b = bh >> 4, h = bh & 15, kvh = h >> 2;
  const int q0 = (w & 7) * 128;
  const int tid = threadIdx.x, lane = tid & 63, wid = tid >> 6;
  const int l16 = lane & 15, kb = (lane >> 4) * 8, r4 = (lane >> 4) * 4;
  __shared__ unsigned short KsL[64 * 128];
  __shared__ unsigned short VTL[128 * 64];
  __shared__ unsigned short PsL[8 * 16 * 64];
  const int sr0 = tid >> 4;
  const int scc = (tid & 15) * 8;

  const unsigned short* qrow =
      q + ((size_t)(b * 16 + h) * 1024 + q0 + wid * 16 + l16) * 128;
  bf16x8 qf[4];
  #pragma unroll
  for (int ks = 0; ks < 4; ++ks) qf[ks] = *(const bf16x8*)&qrow[ks * 32 + kb];
  float mrow[4] = {-1e30f, -1e30f, -1e30f, -1e30f};
  float lrow[4] = {0.f, 0.f, 0.f, 0.f};
  f32x4 oacc[8] = {};
  const unsigned short* kb_base = kbuf + (size_t)(b * 4 + kvh) * SK * 128;
  const unsigned short* vb_base = vbuf + (size_t)(b * 4 + kvh) * SK * 128;

  u16x8 k0[2], v0[2], k1[2], v1[2];

#define ATT_LOAD(kr, vr, kt1)                                                 \
  {                                                                           \
    _Pragma("unroll")                                                         \
    for (int i = 0; i < 2; ++i) {                                             \
      kr[i] = *(const u16x8*)&kb_base[(size_t)((kt1) + sr0 + 32 * i) * 128 + scc]; \
      vr[i] = *(const u16x8*)&vb_base[(size_t)((kt1) + sr0 + 32 * i) * 128 + scc]; \
    }                                                                         \
  }

#define ATT_STAGE(kr, vr)                                                     \
  {                                                                           \
    _Pragma("unroll")                                                         \
    for (int i = 0; i < 2; ++i) {                                             \
      int rr = sr0 + 32 * i;                                                  \
      *(u16x8*)&KsL[rr * 128 + (((scc >> 3) ^ (rr & 7)) << 3)] = kr[i];       \
      _Pragma("unroll")                                                       \
      for (int j = 0; j < 8; ++j)                                             \
        VTL[(scc + j) * 64 + ((((rr >> 3) ^ ((scc + j) >> 3)) & 7) << 3) + (rr & 7)] = vr[i][j]; \
    }                                                                         \
  }

  auto compute = [&]() {
    f32x4 sacc[4] = {};
    __builtin_amdgcn_s_setprio(1);
    #pragma unroll
    for (int ks = 0; ks < 4; ++ks) {
      #pragma unroll
      for (int ni = 0; ni < 4; ++ni) {
        int rr = ni * 16 + l16;
        bf16x8 kf = *(const bf16x8*)
            &KsL[rr * 128 + ((((ks * 32 + kb) >> 3) ^ (rr & 7)) << 3)];
        sacc[ni] = __builtin_amdgcn_mfma_f32_16x16x32_bf16(qf[ks], kf, sacc[ni], 0, 0, 0);
      }
    }
    __builtin_amdgcn_s_setprio(0);
    float pv[4][4], alpha[4];
    #pragma unroll
    for (int r = 0; r < 4; ++r) {
      float tm = fmaxf(fmaxf(sacc[0][r], sacc[1][r]), fmaxf(sacc[2][r], sacc[3][r]));
      #pragma unroll
      for (int off = 1; off < 16; off <<= 1) tm = fmaxf(tm, __shfl_xor(tm, off));
      float mn = fmaxf(mrow[r], tm);
      alpha[r] = __expf(mrow[r] - mn);
      float s = 0.f;
      #pragma unroll
      for (int ni = 0; ni < 4; ++ni) {
        float p = __expf(sacc[ni][r] - mn);
        pv[ni][r] = p; s += p;
      }
      #pragma unroll
      for (int off = 1; off < 16; off <<= 1) s += __shfl_xor(s, off);
      lrow[r] = lrow[r] * alpha[r] + s;
      mrow[r] = mn;
    }
    #pragma unroll
    for (int ni = 0; ni < 8; ++ni)
      #pragma unroll
      for (int r = 0; r < 4; ++r) oacc[ni][r] *= alpha[r];
    #pragma unroll
    for (int ni = 0; ni < 4; ++ni)
      #pragma unroll
      for (int r = 0; r < 4; ++r) {
        int row = r4 + r, col = ni * 16 + l16;
        PsL[wid * 1024 + row * 64 + ((((col >> 3) ^ (row & 7)) & 7) << 3) + (col & 7)]
            = f2bf(pv[ni][r]);
      }
    asm volatile("s_waitcnt lgkmcnt(0)" ::: "memory");
    __builtin_amdgcn_sched_barrier(0);
    __builtin_amdgcn_s_setprio(1);
    #pragma unroll
    for (int ks = 0; ks < 2; ++ks) {
      bf16x8 pf = *(const bf16x8*)
          &PsL[wid * 1024 + l16 * 64 + ((((ks * 32 + kb) >> 3) ^ (l16 & 7)) << 3)];
      #pragma unroll
      for (int ni = 0; ni < 8; ++ni) {
        int d = ni * 16 + l16;
        bf16x8 vf = *(const bf16x8*)
            &VTL[d * 64 + ((((ks * 32 + kb) >> 3) ^ ((d >> 3) & 7)) << 3)];
        oacc[ni] = __builtin_amdgcn_mfma_f32_16x16x32_bf16(pf, vf, oacc[ni], 0, 0, 0);
      }
    }
    __builtin_amdgcn_s_setprio(0);
  };

  ATT_LOAD(k0, v0, 0);
  for (int t = 0; t < 24; t += 2) {
    ATT_STAGE(k0, v0);
    ATT_LOAD(k1, v1, (t + 1) * 64);
    asm volatile("s_waitcnt lgkmcnt(0)" ::: "memory");
    __builtin_amdgcn_s_barrier();
    __builtin_amdgcn_sched_barrier(0);
    compute();
    __builtin_amdgcn_sched_barrier(0);
    __builtin_amdgcn_s_barrier();
    ATT_STAGE(k1, v1);
    if (t + 2 < 24) ATT_LOAD(k0, v0, (t + 2) * 64);
    asm volatile("s_waitcnt lgkmcnt(0)" ::: "memory");
    __builtin_amdgcn_s_barrier();
    __builtin_amdgcn_sched_barrier(0);
    compute();
    __builtin_amdgcn_sched_barrier(0);
    __builtin_amdgcn_s_barrier();
  }
#undef ATT_LOAD
#undef ATT_STAGE

  #pragma unroll
  for (int ni = 0; ni < 8; ++ni)
    #pragma unroll
    for (int r = 0; r < 4; ++r) {
      float val = oacc[ni][r] / lrow[r];
      size_t row = (size_t)b * 1024 + q0 + wid * 16 + r4 + r;
      o[row * 2048 + h * 128 + ni * 16 + l16] = f2bf(val);
    }
}

__global__ void scan_offsets(const int* __restrict__ counts, int* __restrict__ offsets)
{
  if (threadIdx.x == 0 && blockIdx.x == 0) {
    int a = 0;
    for (int e = 0; e < 8; ++e) { offsets[e] = a; a += counts[e]; }
    offsets[8] = a;
  }
}

__global__ __launch_bounds__(256) void scatter_pairs(
    const int* __restrict__ topi, const int* __restrict__ offsets,
    int* __restrict__ fill, int* __restrict__ pair_token, int* __restrict__ token_slot)
{
  int t = blockIdx.x * 256 + threadIdx.x;
  if (t >= 2048) return;
  #pragma unroll
  for (int k = 0; k < 2; ++k) {
    int e = topi[2 * t + k];
    int slot = offsets[e] + atomicAdd(&fill[e], 1);
    pair_token[slot] = t;
    token_slot[2 * t + k] = slot;
  }
}

// act_silu over summed split-K partials: g/u = gu0 + gu1.
__global__ __launch_bounds__(256) void act_silu2(
    const float* __restrict__ gu0, const float* __restrict__ gu1,
    unsigned short* __restrict__ act)
{
  int p = blockIdx.x;
  int c = threadIdx.x * 4;
  float4 g0 = *(const float4*)&gu0[(size_t)p * 2048 + c];
  float4 g1 = *(const float4*)&gu1[(size_t)p * 2048 + c];
  float4 u0 = *(const float4*)&gu0[(size_t)p * 2048 + 1024 + c];
  float4 u1 = *(const float4*)&gu1[(size_t)p * 2048 + 1024 + c];
  float gg[4] = {g0.x + g1.x, g0.y + g1.y, g0.z + g1.z, g0.w + g1.w};
  float uu[4] = {u0.x + u1.x, u0.y + u1.y, u0.z + u1.z, u0.w + u1.w};
  #pragma unroll
  for (int j = 0; j < 4; ++j) {
    float a = gg[j] / (1.f + __expf(-gg[j])) * uu[j];
    act[(size_t)p * 1024 + c + j] = f2bf(a);
  }
}

// combine over summed split-K partials: eo = eo0 + eo1.
__global__ __launch_bounds__(256) void moe_combine2(
    float* __restrict__ out, const float* __restrict__ eo0,
    const float* __restrict__ eo1,
    const int* __restrict__ token_slot, const float* __restrict__ topw)
{
  int t = blockIdx.x;
  int c = threadIdx.x * 8;
  int s0 = token_slot[2 * t], s1 = token_slot[2 * t + 1];
  float w0 = topw[2 * t], w1 = topw[2 * t + 1];
  #pragma unroll
  for (int j0 = 0; j0 < 8; j0 += 4) {
    float4 a0 = *(const float4*)&eo0[(size_t)s0 * 2048 + c + j0];
    float4 a1 = *(const float4*)&eo1[(size_t)s0 * 2048 + c + j0];
    float4 b0 = *(const float4*)&eo0[(size_t)s1 * 2048 + c + j0];
    float4 b1 = *(const float4*)&eo1[(size_t)s1 * 2048 + c + j0];
    float4 v = *(const float4*)&out[(size_t)t * 2048 + c + j0];
    v.x += w0 * (a0.x + a1.x) + w1 * (b0.x + b1.x);
    v.y += w0 * (a0.y + a1.y) + w1 * (b0.y + b1.y);
    v.z += w0 * (a0.z + a1.z) + w1 * (b0.z + b1.z);
    v.w += w0 * (a0.w + a1.w) + w1 * (b0.w + b1.w);
    *(float4*)&out[(size_t)t * 2048 + c + j0] = v;
  }
}

// ---------------------------------------------------------------------------
extern "C" void kernel_launch(void* const* d_in, const int* in_sizes, int n_in,
                              void* d_out, int out_size, void* d_ws, size_t ws_size,
                              hipStream_t stream)
{
  const float* hidden  = (const float*)d_in[0];
  const float* enc     = (const float*)d_in[1];
  const float* img_cos = (const float*)d_in[2];
  const float* img_sin = (const float*)d_in[3];
  const float* txt_cos = (const float*)d_in[4];
  const float* txt_sin = (const float*)d_in[5];
  const float* norm1_w = (const float*)d_in[6];
  const float* norm2_w = (const float*)d_in[7];
  const float* wq      = (const float*)d_in[8];
  const float* wk      = (const float*)d_in[9];
  const float* wv      = (const float*)d_in[10];
  const float* wk_txt  = (const float*)d_in[11];
  const float* wv_txt  = (const float*)d_in[12];
  const float* wo      = (const float*)d_in[13];
  const float* q_norm_w       = (const float*)d_in[14];
  const float* k_norm_w       = (const float*)d_in[15];
  const float* added_k_norm_w = (const float*)d_in[16];
  const float* router_w       = (const float*)d_in[17];
  const float* gate_up_proj   = (const float*)d_in[18];
  const float* down_proj      = (const float*)d_in[19];
  float* out = (float*)d_out;

  char* ws = (char*)d_ws;
  size_t off = 0;
  auto alloc = [&](size_t bytes) {
    void* p = ws + off;
    off += (bytes + 255) & ~(size_t)255;
    return p;
  };
  // --- bf16 transposed weights ---
  unsigned short* wqkvT  = (unsigned short*)alloc(3072ULL * 2048 * 2); // q|k|v rows
  unsigned short* wkvtT  = (unsigned short*)alloc(1024ULL * 2048 * 2); // k_txt|v_txt
  unsigned short* woT    = (unsigned short*)alloc(2048ULL * 2048 * 2);
  unsigned short* gupT   = (unsigned short*)alloc(8ULL * 2048 * 2048 * 2);
  unsigned short* dnT    = (unsigned short*)alloc(8ULL * 2048 * 1024 * 2);
  // --- activations ---
  unsigned short* x_bf   = (unsigned short*)alloc(2048ULL * 2048 * 2);
  unsigned short* enc_bf = (unsigned short*)alloc(1024ULL * 2048 * 2);
  float* gu0  = (float*)alloc(4096ULL * 2048 * 4);  // split-K partial 0
  float* gu1  = (float*)alloc(4096ULL * 2048 * 4);  // split-K partial 1
  unsigned short* qb   = (unsigned short*)alloc(2048ULL * 2048 * 2);
  unsigned short* kbuf = (unsigned short*)alloc(2ULL * 4 * 1536 * 128 * 2);
  unsigned short* vbuf = (unsigned short*)alloc(2ULL * 4 * 1536 * 128 * 2);
  unsigned short* obuf = (unsigned short*)alloc(2048ULL * 2048 * 2);
  unsigned short* act  = obuf;                     // alias (obuf dead after wo GEMM)
  unsigned short* xt   = (unsigned short*)alloc(2048ULL * 2048 * 2);
  int*   ctrl  = (int*)alloc(64 * sizeof(int));    // counts[8] fill[8] offsets[9]
  int*   topi  = (int*)alloc(4096 * 4);
  float* topw  = (float*)alloc(4096 * 4);
  int*   tslot = (int*)alloc(4096 * 4);
  int*   ptok  = (int*)alloc(4096 * 4);
  unsigned short* zbuf = (unsigned short*)alloc(256);
  int* counts = ctrl, * fill = ctrl + 8, * offsets = ctrl + 16;

  hipMemsetAsync(ctrl, 0, 64, stream);
  hipMemsetAsync(zbuf, 0, 256, stream);

  const float scale = 0.08838834764831845f;  // 1/sqrt(128)

  // --- batched weight preprocessing: f32 [K][N] -> bf16 [N][K] ---
  CvtJobs jb;
  jb.src[0] = wq;     jb.dst[0] = wqkvT;                  jb.K[0] = 2048; jb.N[0] = 2048;
  jb.src[1] = wk;     jb.dst[1] = wqkvT + 2048ULL * 2048; jb.K[1] = 2048; jb.N[1] = 512;
  jb.src[2] = wv;     jb.dst[2] = wqkvT + 2560ULL * 2048; jb.K[2] = 2048; jb.N[2] = 512;
  jb.src[3] = wk_txt; jb.dst[3] = wkvtT;                  jb.K[3] = 2048; jb.N[3] = 512;
  jb.src[4] = wv_txt; jb.dst[4] = wkvtT + 512ULL * 2048;  jb.K[4] = 2048; jb.N[4] = 512;
  jb.src[5] = wo;     jb.dst[5] = woT;                    jb.K[5] = 2048; jb.N[5] = 2048;
  jb.src[6] = gate_up_proj; jb.dst[6] = gupT;             jb.K[6] = 2048; jb.N[6] = 2048;
  jb.src[7] = down_proj;    jb.dst[7] = dnT;              jb.K[7] = 1024; jb.N[7] = 2048;
  jb.off[0] = 0;     jb.off[1] = 1024;  jb.off[2] = 1280; jb.off[3] = 1536;
  jb.off[4] = 1792;  jb.off[5] = 2048;  jb.off[6] = 3072; jb.off[7] = 11264;
  jb.off[8] = 15360;
  convert_all<<<15360, 256, 0, stream>>>(jb);

  rmsnorm_rows<<<2048, 256, 0, stream>>>(hidden, norm1_w, x_bf);
  f32_to_bf16_k<<<2048, 256, 0, stream>>>(enc, enc_bf, 1024 * 2048);

  Epi ep;
  ep.qb = qb; ep.kbuf = kbuf; ep.vbuf = vbuf;
  ep.q_nw = q_norm_w; ep.k_nw = k_norm_w; ep.kt_nw = added_k_norm_w;
  ep.icos = img_cos; ep.isin = img_sin; ep.tcos = txt_cos; ep.tsin = txt_sin;
  ep.scale = scale;

  // fused qkv projection + head-norm/rope/relayout epilogue
  gemm_bb<<<384, 256, 0, stream>>>(x_bf, wqkvT, nullptr, nullptr, 2048, 3072, 2048, 1, ep);
  // fused k/v txt projection + epilogue
  gemm_bb<<<64, 256, 0, stream>>>(enc_bf, wkvtT, nullptr, nullptr, 1024, 1024, 2048, 2, ep);

  attn_kernel<<<256, 512, 0, stream>>>(qb, kbuf, vbuf, obuf);

  gemm_bb<<<256, 256, 0, stream>>>(obuf, woT, out, hidden, 2048, 2048, 2048, 0, ep);

  rmsnorm_router<<<2048, 256, 0, stream>>>(out, norm2_w, xt, router_w,
                                           topi, topw, counts);
  scan_offsets<<<1, 64, 0, stream>>>(counts, offsets);
  scatter_pairs<<<8, 256, 0, stream>>>(topi, offsets, fill, ptok, tslot);

  // gate_up: split-K=2 into gu0/gu1
  gemm_moe_256sk<<<1024, 512, 0, stream>>>(xt, gupT, gu0, gu1,
                                           counts, offsets, ptok, zbuf, 1, 2048, 2048);
  act_silu2<<<4096, 256, 0, stream>>>(gu0, gu1, act);
  // down: split-K=2 into gu0/gu1 (reused as eo partials)
  gemm_moe_256sk<<<1024, 512, 0, stream>>>(act, dnT, gu0, gu1,
                                           counts, offsets, ptok, zbuf, 0, 1024, 2048);
  moe_combine2<<<2048, 256, 0, stream>>>(out, gu0, gu1, tslot, topw);
}

// Round 14
// 512.664 us; speedup vs baseline: 1.2743x; 1.0898x over previous
//
#include <hip/hip_runtime.h>

// ---------------------------------------------------------------------------
// NucleusMoEImageTransformerBlock round 14.
// B=2 SI=1024 ST=512 D=2048 H=16 KV=4 HD=128 E=8 F=1024 TOPK=2
// Round-14: (1) MoE GEMM moved to the counted-vmcnt double-buffer pipeline
// (129 KB LDS, 1 blk/CU); (2) split-K partials stored as bf16 (halves the
// gu/eo partial traffic, ~95 MB); (3) launch fusion: pre_norm (rmsnorm +
// enc convert), route_build (scan+scatter, single block, LDS atomics).
// 14 -> 12 dispatches. Everything else unchanged from r13.
// ---------------------------------------------------------------------------

typedef __attribute__((ext_vector_type(8))) __bf16 bf16x8;
typedef __attribute__((ext_vector_type(8))) unsigned short u16x8;
typedef __attribute__((ext_vector_type(4))) unsigned short u16x4;
typedef __attribute__((ext_vector_type(4))) float f32x4;

__device__ __forceinline__ unsigned short f2bf(float x) {
  unsigned u = __builtin_bit_cast(unsigned, x);
  u += 0x7fffu + ((u >> 16) & 1u);        // RNE
  return (unsigned short)(u >> 16);
}
__device__ __forceinline__ float bf2f(unsigned short b) {
  return __builtin_bit_cast(float, ((unsigned)b) << 16);
}

__device__ __forceinline__ void glds16(const unsigned short* g, unsigned short* l) {
  __builtin_amdgcn_global_load_lds(
      (const __attribute__((address_space(1))) void*)g,
      (__attribute__((address_space(3))) void*)l, 16, 0, 0);
}

// m204 bijective XCD chunk swizzle.
__device__ __forceinline__ int xcd_swz(int orig, int nwg) {
  int q = nwg >> 3, r = nwg & 7;
  int xcd = orig & 7, idx = orig >> 3;
  int base = (xcd < r) ? xcd * (q + 1) : r * (q + 1) + (xcd - r) * q;
  return base + idx;
}

// ---------------------------------------------------------------------------
// Batched weight convert+transpose: 8 jobs, W f32 [K][N] -> WT bf16 [N][K].
// ---------------------------------------------------------------------------
struct CvtJobs {
  const float* src[8];
  unsigned short* dst[8];
  int K[8];
  int N[8];
  int off[9];
};

__global__ __launch_bounds__(256) void convert_all(CvtJobs jb)
{
  __shared__ unsigned short T[64][66];
  const int bid = blockIdx.x;
  int j = 0;
  #pragma unroll
  for (int i = 0; i < 8; ++i) if (bid >= jb.off[i + 1]) j = i + 1;
  const int local = bid - jb.off[j];
  const int K = jb.K[j], N = jb.N[j];
  const int kb = K >> 6, nb = N >> 6;
  const int kt = local % kb;
  const int rest = local / kb;
  const int nt = rest % nb, zi = rest / nb;
  const float* Wz = jb.src[j] + (size_t)zi * K * N;
  unsigned short* WTz = jb.dst[j] + (size_t)zi * K * N;
  const int k0 = kt * 64, n0 = nt * 64;
  const int tid = threadIdx.x;
  #pragma unroll
  for (int i = tid; i < 64 * 16; i += 256) {
    int k = i >> 4, n4 = (i & 15) * 4;
    float4 v = *(const float4*)&Wz[(size_t)(k0 + k) * N + n0 + n4];
    T[n4 + 0][k] = f2bf(v.x);
    T[n4 + 1][k] = f2bf(v.y);
    T[n4 + 2][k] = f2bf(v.z);
    T[n4 + 3][k] = f2bf(v.w);
  }
  __syncthreads();
  #pragma unroll
  for (int i = tid; i < 64 * 8; i += 256) {
    int n = i >> 3, k8 = (i & 7) * 8;
    *(u16x8*)&WTz[(size_t)(n0 + n) * K + k0 + k8] = *(const u16x8*)&T[n][k8];
  }
}

// ---------------------------------------------------------------------------
// Epilogue argument bundle for gemm_bb modes 1/2.
// ---------------------------------------------------------------------------
struct Epi {
  unsigned short* qb;
  unsigned short* kbuf;
  unsigned short* vbuf;
  const float* q_nw;
  const float* k_nw;
  const float* kt_nw;
  const float* icos;
  const float* isin;
  const float* tcos;
  const float* tsin;
  float scale;
};

// ---------------------------------------------------------------------------
// Dense GEMM (modes as r13): 128x128 tile, counted-vmcnt dbuf pipeline.
// ---------------------------------------------------------------------------
__global__ __launch_bounds__(256) void gemm_bb(
    const unsigned short* __restrict__ A, const unsigned short* __restrict__ BT,
    float* __restrict__ C, const float* __restrict__ resid,
    int M, int N, int K, int mode, Epi ep)
{
  __shared__ unsigned short As[2][128 * 64];
  __shared__ unsigned short Bs[2][128 * 64];
  const int mb = M >> 7;
  const int w = xcd_swz(blockIdx.x, gridDim.x);
  const int bm = (w % mb) * 128, bn = (w / mb) * 128;
  const int tid = threadIdx.x, lane = tid & 63, wid = tid >> 6;
  const int wm = (wid >> 1) * 64, wn = (wid & 1) * 64;
  const int l16 = lane & 15, g4 = lane >> 4;
  const int rseg = lane >> 3;
  const int csw  = ((lane & 7) ^ rseg) * 8;
  const unsigned short* aSrc[4];
  const unsigned short* bSrc[4];
  #pragma unroll
  for (int p = 0; p < 4; ++p) {
    int row = (p * 4 + wid) * 8 + rseg;
    aSrc[p] = A  + (size_t)(bm + row) * K + csw;
    bSrc[p] = BT + (size_t)(bn + row) * K + csw;
  }
  f32x4 acc[4][4] = {};
  const int NT = K >> 6;
  #pragma unroll
  for (int p = 0; p < 4; ++p) glds16(aSrc[p], &As[0][(p * 4 + wid) * 512]);
  #pragma unroll
  for (int p = 0; p < 4; ++p) glds16(bSrc[p], &Bs[0][(p * 4 + wid) * 512]);
  for (int t = 0; t < NT; ++t) {
    const int cur = t & 1;
    if (t + 1 < NT) {
      const int k0 = (t + 1) << 6;
      #pragma unroll
      for (int p = 0; p < 4; ++p) glds16(aSrc[p] + k0, &As[cur ^ 1][(p * 4 + wid) * 512]);
      #pragma unroll
      for (int p = 0; p < 4; ++p) glds16(bSrc[p] + k0, &Bs[cur ^ 1][(p * 4 + wid) * 512]);
      asm volatile("s_waitcnt vmcnt(8)" ::: "memory");
    } else {
      asm volatile("s_waitcnt vmcnt(0)" ::: "memory");
    }
    __builtin_amdgcn_s_barrier();
    __builtin_amdgcn_sched_barrier(0);
    const unsigned short* ab = &As[cur][0];
    const unsigned short* bb = &Bs[cur][0];
    #pragma unroll
    for (int ks = 0; ks < 2; ++ks) {
      bf16x8 af[4], bf[4];
      #pragma unroll
      for (int i = 0; i < 4; ++i) {
        int ra = wm + i * 16 + l16;
        int rb = wn + i * 16 + l16;
        int ch = ((ks * 4 + g4) ^ (l16 & 7)) * 8;
        af[i] = *(const bf16x8*)&ab[ra * 64 + ch];
        bf[i] = *(const bf16x8*)&bb[rb * 64 + ch];
      }
      #pragma unroll
      for (int mi = 0; mi < 4; ++mi)
        #pragma unroll
        for (int ni = 0; ni < 4; ++ni)
          acc[mi][ni] = __builtin_amdgcn_mfma_f32_16x16x32_bf16(af[mi], bf[ni], acc[mi][ni], 0, 0, 0);
    }
    __builtin_amdgcn_sched_barrier(0);
    __builtin_amdgcn_s_barrier();
  }
  const int r4 = g4 * 4;

  if (mode == 0) {
    #pragma unroll
    for (int mi = 0; mi < 4; ++mi)
      #pragma unroll
      for (int ni = 0; ni < 4; ++ni)
        #pragma unroll
        for (int r = 0; r < 4; ++r) {
          int row = bm + wm + mi * 16 + r4 + r;
          int col = bn + wn + ni * 16 + l16;
          float v = acc[mi][ni][r];
          if (resid) v += resid[(size_t)row * N + col];
          C[(size_t)row * N + col] = v;
        }
    return;
  }

  // ---- fused head-norm / rope / relayout epilogue (modes 1,2) ----
  const int bt = bn >> 7;
  unsigned short* dst;
  const float* nw = nullptr;
  const float* cosT = nullptr;
  const float* sinT = nullptr;
  int h, NH, st, soff, vkind = 0, shift;
  float premul = 1.f;
  int S;
  if (mode == 1) {
    S = 1024; shift = 10;
    if (bt < 16)      { h = bt;      dst = ep.qb;   nw = ep.q_nw; cosT = ep.icos; sinT = ep.isin;
                        NH = 16; st = 1024; soff = 0; premul = ep.scale; }
    else if (bt < 20) { h = bt - 16; dst = ep.kbuf; nw = ep.k_nw; cosT = ep.icos; sinT = ep.isin;
                        NH = 4;  st = 1536; soff = 0; }
    else              { h = bt - 20; dst = ep.vbuf; vkind = 1; NH = 4; st = 1536; soff = 0; }
  } else {
    S = 512; shift = 9;
    if (bt < 4) { h = bt;     dst = ep.kbuf; nw = ep.kt_nw; cosT = ep.tcos; sinT = ep.tsin;
                  NH = 4; st = 1536; soff = 1024; }
    else        { h = bt - 4; dst = ep.vbuf; vkind = 1; NH = 4; st = 1536; soff = 1024; }
  }

  if (vkind) {
    #pragma unroll
    for (int mi = 0; mi < 4; ++mi)
      #pragma unroll
      for (int ni = 0; ni < 4; ++ni)
        #pragma unroll
        for (int r = 0; r < 4; ++r) {
          int row = wm + mi * 16 + r4 + r;
          int d   = wn + ni * 16 + l16;
          int token = bm + row;
          int srow = token & (S - 1), bidx = token >> shift;
          dst[((size_t)(bidx * NH + h) * st + srow + soff) * 128 + d] = f2bf(acc[mi][ni][r]);
        }
    return;
  }

  float* ssb = (float*)&As[0][0];
  float ssp[4][4];
  #pragma unroll
  for (int mi = 0; mi < 4; ++mi)
    #pragma unroll
    for (int r = 0; r < 4; ++r) {
      float v = 0.f;
      #pragma unroll
      for (int ni = 0; ni < 4; ++ni) v += acc[mi][ni][r] * acc[mi][ni][r];
      #pragma unroll
      for (int off = 1; off < 16; off <<= 1) v += __shfl_xor(v, off);
      ssp[mi][r] = v;
    }
  __syncthreads();
  if (l16 == 0) {
    #pragma unroll
    for (int mi = 0; mi < 4; ++mi)
      #pragma unroll
      for (int r = 0; r < 4; ++r)
        ssb[(wid & 1) * 128 + wm + mi * 16 + r4 + r] = ssp[mi][r];
  }
  __syncthreads();
  #pragma unroll
  for (int mi = 0; mi < 4; ++mi)
    #pragma unroll
    for (int r = 0; r < 4; ++r) {
      int row = wm + mi * 16 + r4 + r;
      float tot = ssb[row] + ssb[128 + row];
      float inv = rsqrtf(tot * (1.f / 128.f) + 1e-6f);
      int token = bm + row;
      int srow = token & (S - 1), bidx = token >> shift;
      #pragma unroll
      for (int ni = 0; ni < 4; ++ni) {
        int d = wn + ni * 16 + l16;
        float y = acc[mi][ni][r] * inv * nw[d];
        float part = __shfl_xor(y, 1);
        float c  = cosT[srow * 64 + (d >> 1)];
        float sn = sinT[srow * 64 + (d >> 1)];
        float outv = (d & 1) ? (part * sn + y * c) : (y * c - part * sn);
        dst[((size_t)(bidx * NH + h) * st + srow + soff) * 128 + d] = f2bf(outv * premul);
      }
    }
}

// ---------------------------------------------------------------------------
// Expert-batched MoE GEMM, 256x256 tile, split-K=2, counted-vmcnt dbuf,
// bf16 partial outputs. Grid 1024 = 8bm x 2kh x 8bn x 8e, XCD-swizzled.
// ---------------------------------------------------------------------------
__global__ __launch_bounds__(512, 1) void gemm_moe_256sk(
    const unsigned short* __restrict__ A, const unsigned short* __restrict__ BTall,
    unsigned short* __restrict__ C0, unsigned short* __restrict__ C1,
    const int* __restrict__ counts, const int* __restrict__ offsets,
    const int* __restrict__ pair_token, const unsigned short* __restrict__ zbuf,
    int gather, int K, int N)
{
  const int w = xcd_swz(blockIdx.x, gridDim.x);
  const int e = w >> 7;
  const int local = w & 127;
  const int bm = ((local >> 4) & 7) * 256;
  const int kh = (local >> 3) & 1;
  const int bn = (local & 7) * 256;
  const int cnt = counts[e];
  if (bm >= cnt) return;
  const int base = offsets[e];
  const int Kh = K >> 1;
  unsigned short* __restrict__ C = kh ? C1 : C0;
  __shared__ unsigned short As[2][256 * 64];
  __shared__ unsigned short Bs[2][256 * 64];
  __shared__ int rowmap[256];
  const int tid = threadIdx.x, lane = tid & 63, wid = tid >> 6;
  const int wr = wid >> 2, wc = wid & 3;
  const int l16 = lane & 15, g4 = lane >> 4;
  const int rseg = lane >> 3;
  const int csw  = ((lane & 7) ^ rseg) * 8;
  if (tid < 256) {
    int lr = bm + tid;
    rowmap[tid] = (lr < cnt) ? (gather ? pair_token[base + lr] : base + lr) : -1;
  }
  __syncthreads();
  const unsigned short* BT = BTall + (size_t)e * N * K;
  const unsigned short* aSrc[4];
  const unsigned short* bSrc[4];
  int aOk[4];
  #pragma unroll
  for (int p = 0; p < 4; ++p) {
    int row = (p * 8 + wid) * 8 + rseg;
    int tok = rowmap[row];
    aOk[p] = (tok >= 0);
    aSrc[p] = aOk[p] ? (A + (size_t)tok * K + kh * Kh + csw) : (zbuf + csw);
    bSrc[p] = BT + (size_t)(bn + row) * K + kh * Kh + csw;
  }
  f32x4 acc[8][4] = {};
  const int NT = Kh >> 6;
  #pragma unroll
  for (int p = 0; p < 4; ++p) glds16(aSrc[p], &As[0][(p * 8 + wid) * 512]);
  #pragma unroll
  for (int p = 0; p < 4; ++p) glds16(bSrc[p], &Bs[0][(p * 8 + wid) * 512]);
  for (int t = 0; t < NT; ++t) {
    const int cur = t & 1;
    if (t + 1 < NT) {
      const int k0 = (t + 1) << 6;
      #pragma unroll
      for (int p = 0; p < 4; ++p)
        glds16(aSrc[p] + (aOk[p] ? k0 : 0), &As[cur ^ 1][(p * 8 + wid) * 512]);
      #pragma unroll
      for (int p = 0; p < 4; ++p)
        glds16(bSrc[p] + k0, &Bs[cur ^ 1][(p * 8 + wid) * 512]);
      asm volatile("s_waitcnt vmcnt(8)" ::: "memory");
    } else {
      asm volatile("s_waitcnt vmcnt(0)" ::: "memory");
    }
    __builtin_amdgcn_s_barrier();
    __builtin_amdgcn_sched_barrier(0);
    const unsigned short* ab = &As[cur][0];
    const unsigned short* bb = &Bs[cur][0];
    #pragma unroll
    for (int ks = 0; ks < 2; ++ks) {
      const int ch = ((ks * 4 + g4) ^ (l16 & 7)) * 8;
      bf16x8 bf[4];
      #pragma unroll
      for (int j = 0; j < 4; ++j)
        bf[j] = *(const bf16x8*)&bb[(wc * 64 + j * 16 + l16) * 64 + ch];
      #pragma unroll
      for (int mi = 0; mi < 8; ++mi) {
        bf16x8 af = *(const bf16x8*)&ab[(wr * 128 + mi * 16 + l16) * 64 + ch];
        #pragma unroll
        for (int ni = 0; ni < 4; ++ni)
          acc[mi][ni] = __builtin_amdgcn_mfma_f32_16x16x32_bf16(af, bf[ni], acc[mi][ni], 0, 0, 0);
      }
    }
    __builtin_amdgcn_sched_barrier(0);
    __builtin_amdgcn_s_barrier();
  }
  const int r4 = g4 * 4;
  #pragma unroll
  for (int mi = 0; mi < 8; ++mi)
    #pragma unroll
    for (int ni = 0; ni < 4; ++ni)
      #pragma unroll
      for (int r = 0; r < 4; ++r) {
        int lrow = bm + wr * 128 + mi * 16 + r4 + r;
        int col  = bn + wc * 64 + ni * 16 + l16;
        if (lrow < cnt)
          C[(size_t)(base + lrow) * N + col] = f2bf(acc[mi][ni][r]);
      }
}

// ---------------------------------------------------------------------------
// pre_norm: rows 0..2047 rmsnorm(hidden)->x_bf; rows 2048..3071 convert enc.
// ---------------------------------------------------------------------------
__global__ __launch_bounds__(256) void pre_norm(
    const float* __restrict__ hidden, const float* __restrict__ w,
    unsigned short* __restrict__ x_bf,
    const float* __restrict__ enc, unsigned short* __restrict__ enc_bf)
{
  const int row = blockIdx.x;
  const int tid = threadIdx.x;
  if (row >= 2048) {
    const int r = row - 2048;
    const float* x = enc + (size_t)r * 2048 + tid * 8;
    unsigned short* o = enc_bf + (size_t)r * 2048 + tid * 8;
    float4 a = *(const float4*)&x[0];
    float4 b = *(const float4*)&x[4];
    o[0] = f2bf(a.x); o[1] = f2bf(a.y); o[2] = f2bf(a.z); o[3] = f2bf(a.w);
    o[4] = f2bf(b.x); o[5] = f2bf(b.y); o[6] = f2bf(b.z); o[7] = f2bf(b.w);
    return;
  }
  const float* x = hidden + (size_t)row * 2048;
  float4 a = *(const float4*)&x[tid * 8];
  float4 b = *(const float4*)&x[tid * 8 + 4];
  float s = a.x*a.x + a.y*a.y + a.z*a.z + a.w*a.w
          + b.x*b.x + b.y*b.y + b.z*b.z + b.w*b.w;
  #pragma unroll
  for (int off = 1; off < 64; off <<= 1) s += __shfl_xor(s, off);
  __shared__ float red[4];
  if ((tid & 63) == 0) red[tid >> 6] = s;
  __syncthreads();
  float inv = rsqrtf((red[0] + red[1] + red[2] + red[3]) * (1.f / 2048.f) + 1e-6f);
  float4 wa = *(const float4*)&w[tid * 8];
  float4 wb = *(const float4*)&w[tid * 8 + 4];
  unsigned short* o = x_bf + (size_t)row * 2048 + tid * 8;
  o[0] = f2bf(a.x * inv * wa.x); o[1] = f2bf(a.y * inv * wa.y);
  o[2] = f2bf(a.z * inv * wa.z); o[3] = f2bf(a.w * inv * wa.w);
  o[4] = f2bf(b.x * inv * wb.x); o[5] = f2bf(b.y * inv * wb.y);
  o[6] = f2bf(b.z * inv * wb.z); o[7] = f2bf(b.w * inv * wb.w);
}

// ---------------------------------------------------------------------------
// Fused RMSNorm(norm2) + router: bf16 xt out + exact-f32 top-2 routing.
// ---------------------------------------------------------------------------
__global__ __launch_bounds__(256) void rmsnorm_router(
    const float* __restrict__ in, const float* __restrict__ w,
    unsigned short* __restrict__ xt, const float* __restrict__ rw,
    int* __restrict__ topi, float* __restrict__ topw, int* __restrict__ counts)
{
  const int row = blockIdx.x;
  const int tid = threadIdx.x, lane = tid & 63, wid = tid >> 6;
  const float* x = in + (size_t)row * 2048;
  float4 a = *(const float4*)&x[tid * 8];
  float4 b = *(const float4*)&x[tid * 8 + 4];
  float s = a.x*a.x + a.y*a.y + a.z*a.z + a.w*a.w
          + b.x*b.x + b.y*b.y + b.z*b.z + b.w*b.w;
  #pragma unroll
  for (int off = 1; off < 64; off <<= 1) s += __shfl_xor(s, off);
  __shared__ float red[4];
  __shared__ float rl[4][8];
  if (lane == 0) red[wid] = s;
  __syncthreads();
  float inv = rsqrtf((red[0] + red[1] + red[2] + red[3]) * (1.f / 2048.f) + 1e-6f);
  float4 wa = *(const float4*)&w[tid * 8];
  float4 wb = *(const float4*)&w[tid * 8 + 4];
  float y[8] = {a.x * inv * wa.x, a.y * inv * wa.y, a.z * inv * wa.z, a.w * inv * wa.w,
                b.x * inv * wb.x, b.y * inv * wb.y, b.z * inv * wb.z, b.w * inv * wb.w};
  unsigned short* o = xt + (size_t)row * 2048 + tid * 8;
  #pragma unroll
  for (int j = 0; j < 8; ++j) o[j] = f2bf(y[j]);
  float lg[8] = {};
  #pragma unroll
  for (int j = 0; j < 8; ++j) {
    int d = tid * 8 + j;
    const float4 r0 = *(const float4*)&rw[d * 8];
    const float4 r1 = *(const float4*)&rw[d * 8 + 4];
    lg[0] += y[j] * r0.x; lg[1] += y[j] * r0.y; lg[2] += y[j] * r0.z; lg[3] += y[j] * r0.w;
    lg[4] += y[j] * r1.x; lg[5] += y[j] * r1.y; lg[6] += y[j] * r1.z; lg[7] += y[j] * r1.w;
  }
  #pragma unroll
  for (int e = 0; e < 8; ++e)
    #pragma unroll
    for (int off = 1; off < 64; off <<= 1) lg[e] += __shfl_xor(lg[e], off);
  if (lane == 0) {
    #pragma unroll
    for (int e = 0; e < 8; ++e) rl[wid][e] = lg[e];
  }
  __syncthreads();
  if (tid == 0) {
    float l[8];
    #pragma unroll
    for (int e = 0; e < 8; ++e) l[e] = rl[0][e] + rl[1][e] + rl[2][e] + rl[3][e];
    float v0 = l[0]; int e0 = 0;
    #pragma unroll
    for (int e = 1; e < 8; ++e) if (l[e] > v0) { v0 = l[e]; e0 = e; }
    float v1 = -1e30f; int e1 = 0;
    #pragma unroll
    for (int e = 0; e < 8; ++e) if (e != e0 && l[e] > v1) { v1 = l[e]; e1 = e; }
    float x1 = expf(v1 - v0);
    float w0 = 1.f / (1.f + x1);
    float w1 = x1 / (1.f + x1);
    topi[2 * row] = e0; topi[2 * row + 1] = e1;
    topw[2 * row] = w0; topw[2 * row + 1] = w1;
    atomicAdd(&counts[e0], 1);
    atomicAdd(&counts[e1], 1);
  }
}

// ---------------------------------------------------------------------------
// route_build: single block. Scan counts -> offsets, then scatter pairs via
// LDS atomics. Per-slot content deterministic up to permutation within an
// expert bucket; downstream result is permutation-invariant.
// ---------------------------------------------------------------------------
__global__ __launch_bounds__(256) void route_build(
    const int* __restrict__ counts, int* __restrict__ offsets,
    const int* __restrict__ topi,
    int* __restrict__ pair_token, int* __restrict__ token_slot)
{
  __shared__ int soff[9];
  __shared__ int sfill[8];
  const int tid = threadIdx.x;
  if (tid == 0) {
    int a = 0;
    #pragma unroll
    for (int e = 0; e < 8; ++e) { soff[e] = a; a += counts[e]; }
    soff[8] = a;
  }
  if (tid < 8) sfill[tid] = 0;
  __syncthreads();
  if (tid < 9) offsets[tid] = soff[tid];
  for (int t = tid; t < 2048; t += 256) {
    #pragma unroll
    for (int k = 0; k < 2; ++k) {
      int e = topi[2 * t + k];
      int slot = soff[e] + atomicAdd(&sfill[e], 1);
      pair_token[slot] = t;
      token_slot[2 * t + k] = slot;
    }
  }
}

// ---------------------------------------------------------------------------
// Flash attention (unchanged from r12): 128 q-rows/block, grid 256.
// ---------------------------------------------------------------------------
__global__ __launch_bounds__(512) void attn_kernel(
    const unsigned short* __restrict__ q,
    const unsigned short* __restrict__ kbuf,
    const unsigned short* __restrict__ vbuf,
    unsigned short* __restrict__ o)
{
  const int SK = 1536;
  const int w = xcd_swz(blockIdx.x, gridDim.x);
  const int bh = w >> 3;
  const int b = bh >> 4, h = bh & 15, kvh = h >> 2;
  const int q0 = (w & 7) * 128;
  const int tid = threadIdx.x, lane = tid & 63, wid = tid >> 6;
  const int l16 = lane & 15, kb = (lane >> 4) * 8, r4 = (lane >> 4) * 4;
  __shared__ unsigned short KsL[64 * 128];
  __shared__ unsigned short VTL[128 * 64];
  __shared__ unsigned short PsL[8 * 16 * 64];
  const int sr0 = tid >> 4;
  const int scc = (tid & 15) * 8;

  const unsigned short* qrow =
      q + ((size_t)(b * 16 + h) * 1024 + q0 + wid * 16 + l16) * 128;
  bf16x8 qf[4];
  #pragma unroll
  for (int ks = 0; ks < 4; ++ks) qf[ks] = *(const bf16x8*)&qrow[ks * 32 + kb];
  float mrow[4] = {-1e30f, -1e30f, -1e30f, -1e30f};
  float lrow[4] = {0.f, 0.f, 0.f, 0.f};
  f32x4 oacc[8] = {};
  const unsigned short* kb_base = kbuf + (size_t)(b * 4 + kvh) * SK * 128;
  const unsigned short* vb_base = vbuf + (size_t)(b * 4 + kvh) * SK * 128;

  u16x8 k0[2], v0[2], k1[2], v1[2];

#define ATT_LOAD(kr, vr, kt1)                                                 \
  {                                                                           \
    _Pragma("unroll")                                                         \
    for (int i = 0; i < 2; ++i) {                                             \
      kr[i] = *(const u16x8*)&kb_base[(size_t)((kt1) + sr0 + 32 * i) * 128 + scc]; \
      vr[i] = *(const u16x8*)&vb_base[(size_t)((kt1) + sr0 + 32 * i) * 128 + scc]; \
    }                                                                         \
  }

#define ATT_STAGE(kr, vr)                                                     \
  {                                                                           \
    _Pragma("unroll")                                                         \
    for (int i = 0; i < 2; ++i) {                                             \
      int rr = sr0 + 32 * i;                                                  \
      *(u16x8*)&KsL[rr * 128 + (((scc >> 3) ^ (rr & 7)) << 3)] = kr[i];       \
      _Pragma("unroll")                                                       \
      for (int j = 0; j < 8; ++j)                                             \
        VTL[(scc + j) * 64 + ((((rr >> 3) ^ ((scc + j) >> 3)) & 7) << 3) + (rr & 7)] = vr[i][j]; \
    }                                                                         \
  }

  auto compute = [&]() {
    f32x4 sacc[4] = {};
    __builtin_amdgcn_s_setprio(1);
    #pragma unroll
    for (int ks = 0; ks < 4; ++ks) {
      #pragma unroll
      for (int ni = 0; ni < 4; ++ni) {
        int rr = ni * 16 + l16;
        bf16x8 kf = *(const bf16x8*)
            &KsL[rr * 128 + ((((ks * 32 + kb) >> 3) ^ (rr & 7)) << 3)];
        sacc[ni] = __builtin_amdgcn_mfma_f32_16x16x32_bf16(qf[ks], kf, sacc[ni], 0, 0, 0);
      }
    }
    __builtin_amdgcn_s_setprio(0);
    float pv[4][4], alpha[4];
    #pragma unroll
    for (int r = 0; r < 4; ++r) {
      float tm = fmaxf(fmaxf(sacc[0][r], sacc[1][r]), fmaxf(sacc[2][r], sacc[3][r]));
      #pragma unroll
      for (int off = 1; off < 16; off <<= 1) tm = fmaxf(tm, __shfl_xor(tm, off));
      float mn = fmaxf(mrow[r], tm);
      alpha[r] = __expf(mrow[r] - mn);
      float s = 0.f;
      #pragma unroll
      for (int ni = 0; ni < 4; ++ni) {
        float p = __expf(sacc[ni][r] - mn);
        pv[ni][r] = p; s += p;
      }
      #pragma unroll
      for (int off = 1; off < 16; off <<= 1) s += __shfl_xor(s, off);
      lrow[r] = lrow[r] * alpha[r] + s;
      mrow[r] = mn;
    }
    #pragma unroll
    for (int ni = 0; ni < 8; ++ni)
      #pragma unroll
      for (int r = 0; r < 4; ++r) oacc[ni][r] *= alpha[r];
    #pragma unroll
    for (int ni = 0; ni < 4; ++ni)
      #pragma unroll
      for (int r = 0; r < 4; ++r) {
        int row = r4 + r, col = ni * 16 + l16;
        PsL[wid * 1024 + row * 64 + ((((col >> 3) ^ (row & 7)) & 7) << 3) + (col & 7)]
            = f2bf(pv[ni][r]);
      }
    asm volatile("s_waitcnt lgkmcnt(0)" ::: "memory");
    __builtin_amdgcn_sched_barrier(0);
    __builtin_amdgcn_s_setprio(1);
    #pragma unroll
    for (int ks = 0; ks < 2; ++ks) {
      bf16x8 pf = *(const bf16x8*)
          &PsL[wid * 1024 + l16 * 64 + ((((ks * 32 + kb) >> 3) ^ (l16 & 7)) << 3)];
      #pragma unroll
      for (int ni = 0; ni < 8; ++ni) {
        int d = ni * 16 + l16;
        bf16x8 vf = *(const bf16x8*)
            &VTL[d * 64 + ((((ks * 32 + kb) >> 3) ^ ((d >> 3) & 7)) << 3)];
        oacc[ni] = __builtin_amdgcn_mfma_f32_16x16x32_bf16(pf, vf, oacc[ni], 0, 0, 0);
      }
    }
    __builtin_amdgcn_s_setprio(0);
  };

  ATT_LOAD(k0, v0, 0);
  for (int t = 0; t < 24; t += 2) {
    ATT_STAGE(k0, v0);
    ATT_LOAD(k1, v1, (t + 1) * 64);
    asm volatile("s_waitcnt lgkmcnt(0)" ::: "memory");
    __builtin_amdgcn_s_barrier();
    __builtin_amdgcn_sched_barrier(0);
    compute();
    __builtin_amdgcn_sched_barrier(0);
    __builtin_amdgcn_s_barrier();
    ATT_STAGE(k1, v1);
    if (t + 2 < 24) ATT_LOAD(k0, v0, (t + 2) * 64);
    asm volatile("s_waitcnt lgkmcnt(0)" ::: "memory");
    __builtin_amdgcn_s_barrier();
    __builtin_amdgcn_sched_barrier(0);
    compute();
    __builtin_amdgcn_sched_barrier(0);
    __builtin_amdgcn_s_barrier();
  }
#undef ATT_LOAD
#undef ATT_STAGE

  #pragma unroll
  for (int ni = 0; ni < 8; ++ni)
    #pragma unroll
    for (int r = 0; r < 4; ++r) {
      float val = oacc[ni][r] / lrow[r];
      size_t row = (size_t)b * 1024 + q0 + wid * 16 + r4 + r;
      o[row * 2048 + h * 128 + ni * 16 + l16] = f2bf(val);
    }
}

// act_silu over summed bf16 split-K partials.
__global__ __launch_bounds__(256) void act_silu2(
    const unsigned short* __restrict__ gu0, const unsigned short* __restrict__ gu1,
    unsigned short* __restrict__ act)
{
  int p = blockIdx.x;
  int c = threadIdx.x * 4;
  u16x4 g0 = *(const u16x4*)&gu0[(size_t)p * 2048 + c];
  u16x4 g1 = *(const u16x4*)&gu1[(size_t)p * 2048 + c];
  u16x4 u0 = *(const u16x4*)&gu0[(size_t)p * 2048 + 1024 + c];
  u16x4 u1 = *(const u16x4*)&gu1[(size_t)p * 2048 + 1024 + c];
  #pragma unroll
  for (int j = 0; j < 4; ++j) {
    float g = bf2f(g0[j]) + bf2f(g1[j]);
    float u = bf2f(u0[j]) + bf2f(u1[j]);
    float a = g / (1.f + __expf(-g)) * u;
    act[(size_t)p * 1024 + c + j] = f2bf(a);
  }
}

// combine over summed bf16 split-K partials.
__global__ __launch_bounds__(256) void moe_combine2(
    float* __restrict__ out, const unsigned short* __restrict__ eo0,
    const unsigned short* __restrict__ eo1,
    const int* __restrict__ token_slot, const float* __restrict__ topw)
{
  int t = blockIdx.x;
  int c = threadIdx.x * 8;
  int s0 = token_slot[2 * t], s1 = token_slot[2 * t + 1];
  float w0 = topw[2 * t], w1 = topw[2 * t + 1];
  u16x8 a0 = *(const u16x8*)&eo0[(size_t)s0 * 2048 + c];
  u16x8 a1 = *(const u16x8*)&eo1[(size_t)s0 * 2048 + c];
  u16x8 b0 = *(const u16x8*)&eo0[(size_t)s1 * 2048 + c];
  u16x8 b1 = *(const u16x8*)&eo1[(size_t)s1 * 2048 + c];
  #pragma unroll
  for (int j0 = 0; j0 < 8; j0 += 4) {
    float4 v = *(const float4*)&out[(size_t)t * 2048 + c + j0];
    v.x += w0 * (bf2f(a0[j0+0]) + bf2f(a1[j0+0])) + w1 * (bf2f(b0[j0+0]) + bf2f(b1[j0+0]));
    v.y += w0 * (bf2f(a0[j0+1]) + bf2f(a1[j0+1])) + w1 * (bf2f(b0[j0+1]) + bf2f(b1[j0+1]));
    v.z += w0 * (bf2f(a0[j0+2]) + bf2f(a1[j0+2])) + w1 * (bf2f(b0[j0+2]) + bf2f(b1[j0+2]));
    v.w += w0 * (bf2f(a0[j0+3]) + bf2f(a1[j0+3])) + w1 * (bf2f(b0[j0+3]) + bf2f(b1[j0+3]));
    *(float4*)&out[(size_t)t * 2048 + c + j0] = v;
  }
}

// ---------------------------------------------------------------------------
extern "C" void kernel_launch(void* const* d_in, const int* in_sizes, int n_in,
                              void* d_out, int out_size, void* d_ws, size_t ws_size,
                              hipStream_t stream)
{
  const float* hidden  = (const float*)d_in[0];
  const float* enc     = (const float*)d_in[1];
  const float* img_cos = (const float*)d_in[2];
  const float* img_sin = (const float*)d_in[3];
  const float* txt_cos = (const float*)d_in[4];
  const float* txt_sin = (const float*)d_in[5];
  const float* norm1_w = (const float*)d_in[6];
  const float* norm2_w = (const float*)d_in[7];
  const float* wq      = (const float*)d_in[8];
  const float* wk      = (const float*)d_in[9];
  const float* wv      = (const float*)d_in[10];
  const float* wk_txt  = (const float*)d_in[11];
  const float* wv_txt  = (const float*)d_in[12];
  const float* wo      = (const float*)d_in[13];
  const float* q_norm_w       = (const float*)d_in[14];
  const float* k_norm_w       = (const float*)d_in[15];
  const float* added_k_norm_w = (const float*)d_in[16];
  const float* router_w       = (const float*)d_in[17];
  const float* gate_up_proj   = (const float*)d_in[18];
  const float* down_proj      = (const float*)d_in[19];
  float* out = (float*)d_out;

  char* ws = (char*)d_ws;
  size_t off = 0;
  auto alloc = [&](size_t bytes) {
    void* p = ws + off;
    off += (bytes + 255) & ~(size_t)255;
    return p;
  };
  unsigned short* wqkvT  = (unsigned short*)alloc(3072ULL * 2048 * 2);
  unsigned short* wkvtT  = (unsigned short*)alloc(1024ULL * 2048 * 2);
  unsigned short* woT    = (unsigned short*)alloc(2048ULL * 2048 * 2);
  unsigned short* gupT   = (unsigned short*)alloc(8ULL * 2048 * 2048 * 2);
  unsigned short* dnT    = (unsigned short*)alloc(8ULL * 2048 * 1024 * 2);
  unsigned short* x_bf   = (unsigned short*)alloc(2048ULL * 2048 * 2);
  unsigned short* enc_bf = (unsigned short*)alloc(1024ULL * 2048 * 2);
  unsigned short* gu0 = (unsigned short*)alloc(4096ULL * 2048 * 2);  // bf16 partial 0
  unsigned short* gu1 = (unsigned short*)alloc(4096ULL * 2048 * 2);  // bf16 partial 1
  unsigned short* qb   = (unsigned short*)alloc(2048ULL * 2048 * 2);
  unsigned short* kbuf = (unsigned short*)alloc(2ULL * 4 * 1536 * 128 * 2);
  unsigned short* vbuf = (unsigned short*)alloc(2ULL * 4 * 1536 * 128 * 2);
  unsigned short* obuf = (unsigned short*)alloc(2048ULL * 2048 * 2);
  unsigned short* act  = obuf;                     // alias (obuf dead after wo GEMM)
  unsigned short* xt   = (unsigned short*)alloc(2048ULL * 2048 * 2);
  int*   ctrl  = (int*)alloc(64 * sizeof(int));    // counts[8] offsets[9]
  int*   topi  = (int*)alloc(4096 * 4);
  float* topw  = (float*)alloc(4096 * 4);
  int*   tslot = (int*)alloc(4096 * 4);
  int*   ptok  = (int*)alloc(4096 * 4);
  unsigned short* zbuf = (unsigned short*)alloc(256);
  int* counts = ctrl, * offsets = ctrl + 16;

  hipMemsetAsync(ctrl, 0, 64, stream);
  hipMemsetAsync(zbuf, 0, 256, stream);

  const float scale = 0.08838834764831845f;  // 1/sqrt(128)

  CvtJobs jb;
  jb.src[0] = wq;     jb.dst[0] = wqkvT;                  jb.K[0] = 2048; jb.N[0] = 2048;
  jb.src[1] = wk;     jb.dst[1] = wqkvT + 2048ULL * 2048; jb.K[1] = 2048; jb.N[1] = 512;
  jb.src[2] = wv;     jb.dst[2] = wqkvT + 2560ULL * 2048; jb.K[2] = 2048; jb.N[2] = 512;
  jb.src[3] = wk_txt; jb.dst[3] = wkvtT;                  jb.K[3] = 2048; jb.N[3] = 512;
  jb.src[4] = wv_txt; jb.dst[4] = wkvtT + 512ULL * 2048;  jb.K[4] = 2048; jb.N[4] = 512;
  jb.src[5] = wo;     jb.dst[5] = woT;                    jb.K[5] = 2048; jb.N[5] = 2048;
  jb.src[6] = gate_up_proj; jb.dst[6] = gupT;             jb.K[6] = 2048; jb.N[6] = 2048;
  jb.src[7] = down_proj;    jb.dst[7] = dnT;              jb.K[7] = 1024; jb.N[7] = 2048;
  jb.off[0] = 0;     jb.off[1] = 1024;  jb.off[2] = 1280; jb.off[3] = 1536;
  jb.off[4] = 1792;  jb.off[5] = 2048;  jb.off[6] = 3072; jb.off[7] = 11264;
  jb.off[8] = 15360;
  convert_all<<<15360, 256, 0, stream>>>(jb);

  pre_norm<<<3072, 256, 0, stream>>>(hidden, norm1_w, x_bf, enc, enc_bf);

  Epi ep;
  ep.qb = qb; ep.kbuf = kbuf; ep.vbuf = vbuf;
  ep.q_nw = q_norm_w; ep.k_nw = k_norm_w; ep.kt_nw = added_k_norm_w;
  ep.icos = img_cos; ep.isin = img_sin; ep.tcos = txt_cos; ep.tsin = txt_sin;
  ep.scale = scale;

  gemm_bb<<<384, 256, 0, stream>>>(x_bf, wqkvT, nullptr, nullptr, 2048, 3072, 2048, 1, ep);
  gemm_bb<<<64, 256, 0, stream>>>(enc_bf, wkvtT, nullptr, nullptr, 1024, 1024, 2048, 2, ep);

  attn_kernel<<<256, 512, 0, stream>>>(qb, kbuf, vbuf, obuf);

  gemm_bb<<<256, 256, 0, stream>>>(obuf, woT, out, hidden, 2048, 2048, 2048, 0, ep);

  rmsnorm_router<<<2048, 256, 0, stream>>>(out, norm2_w, xt, router_w,
                                           topi, topw, counts);
  route_build<<<1, 256, 0, stream>>>(counts, offsets, topi, ptok, tslot);

  gemm_moe_256sk<<<1024, 512, 0, stream>>>(xt, gupT, gu0, gu1,
                                           counts, offsets, ptok, zbuf, 1, 2048, 2048);
  act_silu2<<<4096, 256, 0, stream>>>(gu0, gu1, act);
  gemm_moe_256sk<<<1024, 512, 0, stream>>>(act, dnT, gu0, gu1,
                                           counts, offsets, ptok, zbuf, 0, 1024, 2048);
  moe_combine2<<<2048, 256, 0, stream>>>(out, gu0, gu1, tslot, topw);
}